// Round 13
// baseline (243.251 us; speedup 1.0000x reference)
//
#include <hip/hip_runtime.h>
#include <hip/hip_bf16.h>
#include <math.h>

#define GG 2048          // conv grid (colpart rows)
#define RB 32            // colpart rows per stage-A block
#define NB_SHIFT 9       // 512 nodes per bin
#define NPB 512
#define BINCAP 10240     // edges per bin (mean 8192, 6-sigma ~8740)
#define BINREGION 12288  // padded words per bin bucket region (48 KB LDS window)
#define PCHUNK 8192      // edges per partition chunk

typedef __hip_bfloat16 bf16;
typedef unsigned int uint;
typedef unsigned short ushort;
typedef short bf16x8 __attribute__((ext_vector_type(8)));
typedef float f32x4 __attribute__((ext_vector_type(4)));
typedef float f32x2 __attribute__((ext_vector_type(2)));

__device__ __forceinline__ bf16  f2b(float x) { return __float2bfloat16(x); }
__device__ __forceinline__ short f2bs(float x) {
    bf16 b = __float2bfloat16(x);
    return *reinterpret_cast<short*>(&b);
}
// bf16-packed pos/neg (conv outputs H, z)
__device__ __forceinline__ float posf(uint u) { return __uint_as_float(u << 16); }
__device__ __forceinline__ float negf(uint u) { return __uint_as_float(u & 0xFFFF0000u); }
__device__ __forceinline__ uint  packbf(float p, float n) {
    bf16 bp = f2b(p), bn = f2b(n);
    ushort up = *reinterpret_cast<ushort*>(&bp);
    ushort un = *reinterpret_cast<ushort*>(&bn);
    return (uint)up | ((uint)un << 16);
}
// fp8 e4m3-packed pos/neg (conv inputs G): byte0=pos, byte1=neg
__device__ __forceinline__ ushort packfp8(float p, float n) {
    return (ushort)__builtin_amdgcn_cvt_pk_fp8_f32(p, n, 0, false);
}
__device__ __forceinline__ f32x2 unpackfp8(uint u) {
    return __builtin_amdgcn_cvt_pk_f32_fp8((int)u, false);
}

// ---- P1: partition edges into bins of 512 nodes; packed u = (r<<9)|(c&511).
__global__ __launch_bounds__(256) void partition_edges(
        const int* __restrict__ row, const int* __restrict__ col,
        uint* __restrict__ bins, int* __restrict__ bincnt, int E, int nb) {
    __shared__ int lcnt[256];
    __shared__ int lbase[256];
    for (int chunk = blockIdx.x * PCHUNK; chunk < E; chunk += gridDim.x * PCHUNK) {
        int end = chunk + PCHUNK < E ? chunk + PCHUNK : E;
        if (threadIdx.x < nb) lcnt[threadIdx.x] = 0;
        __syncthreads();
        for (int e = chunk + threadIdx.x; e < end; e += 256)
            atomicAdd(&lcnt[col[e] >> NB_SHIFT], 1);
        __syncthreads();
        if (threadIdx.x < nb) {
            lbase[threadIdx.x] = atomicAdd(&bincnt[threadIdx.x], lcnt[threadIdx.x]);
            lcnt[threadIdx.x] = 0;
        }
        __syncthreads();
        for (int e = chunk + threadIdx.x; e < end; e += 256) {
            int c = col[e], r = row[e];
            int g = c >> NB_SHIFT;
            int dst = lbase[g] + atomicAdd(&lcnt[g], 1);
            if (dst < BINCAP)
                bins[(size_t)g * BINCAP + dst] = ((uint)r << NB_SHIFT) | (uint)(c & (NPB - 1));
        }
        __syncthreads();
    }
}

// ---- P2: one block per bin. LDS hist -> cnt; LDS padded prefix -> off;
// LDS-window scatter; coalesced int4 write-out. ------------------------------
__global__ __launch_bounds__(256) void place_lds(
        const uint* __restrict__ bins, const int* __restrict__ bincnt,
        int* __restrict__ bucket, int* __restrict__ off, int* __restrict__ cnt,
        int N) {
    __shared__ int lcnt[NPB];
    __shared__ int s[NPB];
    __shared__ int win[BINREGION];
    int b  = blockIdx.x;
    int lo = b << NB_SHIFT;
    int base = b * BINREGION;
    int ne = bincnt[b];
    if (ne > BINCAP) ne = BINCAP;
    const uint* be = bins + (size_t)b * BINCAP;
    for (int i = threadIdx.x; i < NPB; i += 256) lcnt[i] = 0;
    __syncthreads();
    for (int i = threadIdx.x; i < ne; i += 256)
        atomicAdd(&lcnt[be[i] & (NPB - 1)], 1);
    __syncthreads();
    int i0 = threadIdx.x, i1 = threadIdx.x + 256;
    s[i0] = (lcnt[i0] + 3) & ~3;
    s[i1] = (lcnt[i1] + 3) & ~3;
    __syncthreads();
    for (int st = 1; st < NPB; st <<= 1) {
        int v0 = i0 >= st ? s[i0 - st] : 0;
        int v1 = i1 >= st ? s[i1 - st] : 0;
        __syncthreads();
        s[i0] += v0; s[i1] += v1;
        __syncthreads();
    }
    for (int i = threadIdx.x; i < NPB; i += 256) {
        int v = lo + i;
        int pc = (lcnt[i] + 3) & ~3;
        int start = s[i] - pc;
        if (v < N) { off[v] = base + start; cnt[v] = lcnt[i]; }
        lcnt[i] = start;
    }
    __syncthreads();
    for (int i = threadIdx.x; i < ne; i += 256) {
        uint u = be[i];
        int slot = atomicAdd(&lcnt[u & (NPB - 1)], 1);
        if (slot < BINREGION) win[slot] = (int)(u >> NB_SHIFT);
    }
    __syncthreads();
    int wsize = s[NPB - 1];
    if (wsize > BINREGION) wsize = BINREGION;
    for (int i = threadIdx.x * 4; i < wsize; i += 1024)
        *(int4*)&bucket[base + i] = *(const int4*)&win[i];
}

// ---- layer-1 GEMM via MFMA; fp8-packed output -----------------------------
__global__ __launch_bounds__(256) void gemm1_mfma(
        const float* __restrict__ X, const float* __restrict__ W,
        const int* __restrict__ perm, const int* __restrict__ cnt,
        ushort* __restrict__ out, int n) {
    int lane = threadIdx.x & 63, wid = threadIdx.x >> 6;
    int l15 = lane & 15, lg = lane >> 4;
    bf16x8 bfr[2][4];
#pragma unroll
    for (int kt = 0; kt < 2; kt++)
#pragma unroll
        for (int nt = 0; nt < 4; nt++)
#pragma unroll
            for (int i = 0; i < 8; i++)
                bfr[kt][nt][i] = f2bs(W[(kt * 32 + lg * 8 + i) * 64 + nt * 16 + l15]);
    int ntiles = (n + 15) >> 4;
    for (int t = blockIdx.x * 4 + wid; t < ntiles; t += gridDim.x * 4) {
        int rowA = t * 16 + l15;
        if (rowA >= n) rowA = n - 1;
        int prow = perm[rowA];
        const float4* xp = (const float4*)(X + (size_t)rowA * 64);
        const float4* xn = (const float4*)(X + (size_t)prow * 64);
        bf16x8 ap[2], an[2];
#pragma unroll
        for (int kt = 0; kt < 2; kt++) {
            float4 p0 = xp[kt * 8 + lg * 2], p1 = xp[kt * 8 + lg * 2 + 1];
            float4 n0 = xn[kt * 8 + lg * 2], n1 = xn[kt * 8 + lg * 2 + 1];
            ap[kt][0] = f2bs(p0.x); ap[kt][1] = f2bs(p0.y);
            ap[kt][2] = f2bs(p0.z); ap[kt][3] = f2bs(p0.w);
            ap[kt][4] = f2bs(p1.x); ap[kt][5] = f2bs(p1.y);
            ap[kt][6] = f2bs(p1.z); ap[kt][7] = f2bs(p1.w);
            an[kt][0] = f2bs(n0.x); an[kt][1] = f2bs(n0.y);
            an[kt][2] = f2bs(n0.z); an[kt][3] = f2bs(n0.w);
            an[kt][4] = f2bs(n1.x); an[kt][5] = f2bs(n1.y);
            an[kt][6] = f2bs(n1.z); an[kt][7] = f2bs(n1.w);
        }
        f32x4 accp[4], accn[4];
#pragma unroll
        for (int nt = 0; nt < 4; nt++) { accp[nt] = (f32x4)0.f; accn[nt] = (f32x4)0.f; }
#pragma unroll
        for (int nt = 0; nt < 4; nt++) {
            accp[nt] = __builtin_amdgcn_mfma_f32_16x16x32_bf16(ap[0], bfr[0][nt], accp[nt], 0, 0, 0);
            accp[nt] = __builtin_amdgcn_mfma_f32_16x16x32_bf16(ap[1], bfr[1][nt], accp[nt], 0, 0, 0);
            accn[nt] = __builtin_amdgcn_mfma_f32_16x16x32_bf16(an[0], bfr[0][nt], accn[nt], 0, 0, 0);
            accn[nt] = __builtin_amdgcn_mfma_f32_16x16x32_bf16(an[1], bfr[1][nt], accn[nt], 0, 0, 0);
        }
        float dvr[4];
#pragma unroll
        for (int reg = 0; reg < 4; reg++) {
            int node = t * 16 + lg * 4 + reg;
            dvr[reg] = node < n ? rsqrtf((float)cnt[node] + 1.0f) : 0.f;
        }
#pragma unroll
        for (int nt = 0; nt < 4; nt++)
#pragma unroll
            for (int reg = 0; reg < 4; reg++) {
                int node = t * 16 + lg * 4 + reg;
                if (node < n)
                    out[(size_t)node * 64 + nt * 16 + l15] =
                        packfp8(accp[nt][reg] * dvr[reg], accn[nt][reg] * dvr[reg]);
            }
    }
}

// ---- layer-2 GEMM via MFMA, bf16-packed in, fp8-packed out -----------------
__global__ __launch_bounds__(256) void gemm2_mfma(
        const uint* __restrict__ H, const float* __restrict__ W,
        const int* __restrict__ cnt, ushort* __restrict__ out, int n) {
    int lane = threadIdx.x & 63, wid = threadIdx.x >> 6;
    int l15 = lane & 15, lg = lane >> 4;
    bf16x8 bfr[2][4];
#pragma unroll
    for (int kt = 0; kt < 2; kt++)
#pragma unroll
        for (int nt = 0; nt < 4; nt++)
#pragma unroll
            for (int i = 0; i < 8; i++)
                bfr[kt][nt][i] = f2bs(W[(kt * 32 + lg * 8 + i) * 64 + nt * 16 + l15]);
    int ntiles = (n + 15) >> 4;
    for (int t = blockIdx.x * 4 + wid; t < ntiles; t += gridDim.x * 4) {
        int rowA = t * 16 + l15;
        if (rowA >= n) rowA = n - 1;
        const uint4* h = (const uint4*)(H + (size_t)rowA * 64);
        bf16x8 ap[2], an[2];
#pragma unroll
        for (int kt = 0; kt < 2; kt++) {
            uint4 u0 = h[kt * 8 + lg * 2], u1 = h[kt * 8 + lg * 2 + 1];
            uint uu[8] = {u0.x, u0.y, u0.z, u0.w, u1.x, u1.y, u1.z, u1.w};
#pragma unroll
            for (int i = 0; i < 8; i++) {
                ap[kt][i] = (short)(uu[i] & 0xFFFFu);
                an[kt][i] = (short)(uu[i] >> 16);
            }
        }
        f32x4 accp[4], accn[4];
#pragma unroll
        for (int nt = 0; nt < 4; nt++) { accp[nt] = (f32x4)0.f; accn[nt] = (f32x4)0.f; }
#pragma unroll
        for (int nt = 0; nt < 4; nt++) {
            accp[nt] = __builtin_amdgcn_mfma_f32_16x16x32_bf16(ap[0], bfr[0][nt], accp[nt], 0, 0, 0);
            accp[nt] = __builtin_amdgcn_mfma_f32_16x16x32_bf16(ap[1], bfr[1][nt], accp[nt], 0, 0, 0);
            accn[nt] = __builtin_amdgcn_mfma_f32_16x16x32_bf16(an[0], bfr[0][nt], accn[nt], 0, 0, 0);
            accn[nt] = __builtin_amdgcn_mfma_f32_16x16x32_bf16(an[1], bfr[1][nt], accn[nt], 0, 0, 0);
        }
        float dvr[4];
#pragma unroll
        for (int reg = 0; reg < 4; reg++) {
            int node = t * 16 + lg * 4 + reg;
            dvr[reg] = node < n ? rsqrtf((float)cnt[node] + 1.0f) : 0.f;
        }
#pragma unroll
        for (int nt = 0; nt < 4; nt++)
#pragma unroll
            for (int reg = 0; reg < 4; reg++) {
                int node = t * 16 + lg * 4 + reg;
                if (node < n)
                    out[(size_t)node * 64 + nt * 16 + l15] =
                        packfp8(accp[nt][reg] * dvr[reg], accn[nt][reg] * dvr[reg]);
            }
    }
}

// ---- fused GCN aggregation: 2 dims/lane, 2 rows per wave-gather -----------
// lane = (half<<5)|dl; lane handles dims {2dl, 2dl+1} (one uint of G).
// half 0 gathers even-indexed edges, half 1 odd-indexed; cross-half shfl
// combine at the end. Self + odd tail counted by half 0 only.
template <int MODE>
__global__ __launch_bounds__(256) void conv_packed(
        const ushort* __restrict__ g, const int* __restrict__ bucket,
        const int* __restrict__ off, const int* __restrict__ cnt,
        const float* __restrict__ bias,
        uint* __restrict__ out, float* __restrict__ colpart, int n) {
    int lane = threadIdx.x & 63, wid = threadIdx.x >> 6;
    int half = lane >> 5, dl = lane & 31;
    __shared__ float s[256];
    float colpE = 0.f, colpO = 0.f;
    float bE = bias[2 * dl], bO = bias[2 * dl + 1];
    int wstart = blockIdx.x * 4 + wid, wstride = gridDim.x * 4;
    for (int v = wstart; v < n; v += wstride) {
        int c = cnt[v];
        float dv = rsqrtf((float)c + 1.0f);
        float aEP0 = 0.f, aEN0 = 0.f, aOP0 = 0.f, aON0 = 0.f;
        float aEP1 = 0.f, aEN1 = 0.f, aOP1 = 0.f, aON1 = 0.f;
        if (half == 0) {   // self-loop row, counted once
            uint u = *(const uint*)(g + (size_t)v * 64 + 2 * dl);
            f32x2 dE = unpackfp8(u & 0xFFFFu), dO = unpackfp8(u >> 16);
            aEP0 += dE.x; aEN0 += dE.y; aOP0 += dO.x; aON0 += dO.y;
        }
        const int*  bk  = bucket + off[v];
        const int4* bk4 = (const int4*)bk;
        int nq4 = c >> 2;           // 4 edges = 2 pairs per chunk
        for (int q = 0; q < nq4; q++) {
            int4 r4 = bk4[q];
            int rA = half ? r4.y : r4.x;
            int rB = half ? r4.w : r4.z;
            uint uA = *(const uint*)(g + (size_t)rA * 64 + 2 * dl);
            uint uB = *(const uint*)(g + (size_t)rB * 64 + 2 * dl);
            f32x2 dAE = unpackfp8(uA & 0xFFFFu), dAO = unpackfp8(uA >> 16);
            f32x2 dBE = unpackfp8(uB & 0xFFFFu), dBO = unpackfp8(uB >> 16);
            aEP0 += dAE.x; aEN0 += dAE.y; aOP0 += dAO.x; aON0 += dAO.y;
            aEP1 += dBE.x; aEN1 += dBE.y; aOP1 += dBO.x; aON1 += dBO.y;
        }
        int i = nq4 << 2;
        if (c - i >= 2) {           // one full pair
            int rA = bk[i + half];
            uint uA = *(const uint*)(g + (size_t)rA * 64 + 2 * dl);
            f32x2 dAE = unpackfp8(uA & 0xFFFFu), dAO = unpackfp8(uA >> 16);
            aEP0 += dAE.x; aEN0 += dAE.y; aOP0 += dAO.x; aON0 += dAO.y;
            i += 2;
        }
        if (i < c && half == 0) {   // odd tail edge, half 0 only
            int rA = bk[i];
            uint uA = *(const uint*)(g + (size_t)rA * 64 + 2 * dl);
            f32x2 dAE = unpackfp8(uA & 0xFFFFu), dAO = unpackfp8(uA >> 16);
            aEP0 += dAE.x; aEN0 += dAE.y; aOP0 += dAO.x; aON0 += dAO.y;
        }
        float aEP = aEP0 + aEP1, aEN = aEN0 + aEN1;
        float aOP = aOP0 + aOP1, aON = aON0 + aON1;
        aEP += __shfl_xor(aEP, 32, 64);
        aEN += __shfl_xor(aEN, 32, 64);
        aOP += __shfl_xor(aOP, 32, 64);
        aON += __shfl_xor(aON, 32, 64);
        float rpE = fmaf(dv, aEP, bE), rnE = fmaf(dv, aEN, bE);
        float rpO = fmaf(dv, aOP, bO), rnO = fmaf(dv, aON, bO);
        if (MODE == 0) {
            if (half == 0) {
                uint2 o;
                o.x = packbf(fmaxf(rpE, 0.f), fmaxf(rnE, 0.f));
                o.y = packbf(fmaxf(rpO, 0.f), fmaxf(rnO, 0.f));
                *(uint2*)(out + (size_t)v * 64 + 2 * dl) = o;
            }
        } else {
            if (half == 0) {
                uint2 o;
                o.x = packbf(rpE, rnE);
                o.y = packbf(rpO, rnO);
                *(uint2*)(out + (size_t)v * 64 + 2 * dl) = o;
            }
            colpE += rpE;           // identical on both halves; half0's used
            colpO += rpO;
        }
    }
    if (MODE == 1) {
        if (half == 0) {
            s[wid * 64 + 2 * dl]     = colpE;
            s[wid * 64 + 2 * dl + 1] = colpO;
        }
        __syncthreads();
        if (wid == 0) {
            float t = s[lane] + s[64 + lane] + s[128 + lane] + s[192 + lane];
            colpart[(size_t)blockIdx.x * 64 + lane] = t;
        }
    }
}

// ---- stage A: sum RB colpart rows per block -> colpart2 --------------------
__global__ __launch_bounds__(256) void colreduce_kernel(
        const float* __restrict__ colpart, float* __restrict__ colpart2) {
    int lane = threadIdx.x & 63, w = threadIdx.x >> 6;
    __shared__ float s4[4][64];
    float t = 0.f;
    int base = blockIdx.x * RB;
    for (int g = w; g < RB; g += 4) t += colpart[(size_t)(base + g) * 64 + lane];
    s4[w][lane] = t;
    __syncthreads();
    if (w == 0)
        colpart2[(size_t)blockIdx.x * 64 + lane] =
            s4[0][lane] + s4[1][lane] + s4[2][lane] + s4[3][lane];
}

// ---- summary + ws = W_dgi @ sigmoid(mean(pos_z)) ---------------------------
__global__ void summary_kernel(const float* __restrict__ colpart,
                               const float* __restrict__ Wdgi,
                               float* __restrict__ wsv, int G, float invN) {
    __shared__ float sm[64];
    __shared__ float s4[4][64];
    int lane = threadIdx.x & 63, w = threadIdx.x >> 6;
    float t = 0.f;
    for (int g = w; g < G; g += 4) t += colpart[(size_t)g * 64 + lane];
    s4[w][lane] = t;
    __syncthreads();
    if (w == 0) {
        t = s4[0][lane] + s4[1][lane] + s4[2][lane] + s4[3][lane];
        sm[lane] = 1.f / (1.f + expf(-t * invN));
    }
    __syncthreads();
    if (threadIdx.x < 64) {
        float a = 0.f;
        for (int j = 0; j < 64; j++) a += Wdgi[threadIdx.x * 64 + j] * sm[j];
        wsv[threadIdx.x] = a;
    }
}

// ---- both losses: 16-lane group per node, 4 nodes per wave-iteration -------
__global__ __launch_bounds__(256) void loss4_kernel(
        const uint* __restrict__ z, const float* __restrict__ wsv,
        float* __restrict__ lossacc, int n) {
    int lane = threadIdx.x & 63, wid = threadIdx.x >> 6;
    int sub = lane >> 4, dch = lane & 15;
    __shared__ float s[16];
    float w0 = wsv[dch * 4], w1 = wsv[dch * 4 + 1];
    float w2 = wsv[dch * 4 + 2], w3 = wsv[dch * 4 + 3];
    float lp = 0.f, ln = 0.f;
    int nq = (n + 3) >> 2;
    for (int qi = blockIdx.x * 4 + wid; qi < nq; qi += gridDim.x * 4) {
        int v = qi * 4 + sub;
        float p = 0.f, q = 0.f;
        if (v < n) {
            uint4 u = *(const uint4*)(z + (size_t)v * 64 + dch * 4);
            p = posf(u.x) * w0 + posf(u.y) * w1 + posf(u.z) * w2 + posf(u.w) * w3;
            q = negf(u.x) * w0 + negf(u.y) * w1 + negf(u.z) * w2 + negf(u.w) * w3;
        }
        for (int o = 1; o < 16; o <<= 1) {
            p += __shfl_xor(p, o, 64);
            q += __shfl_xor(q, o, 64);
        }
        if (dch == 0 && v < n) {
            lp += -logf(1.f / (1.f + expf(-p)) + 1e-15f);   // -log(sigmoid(p)+eps)
            ln += -logf(1.f / (1.f + expf( q)) + 1e-15f);   // -log(1-sigmoid(q)+eps)
        }
    }
    lp += __shfl_xor(lp, 16, 64); ln += __shfl_xor(ln, 16, 64);
    lp += __shfl_xor(lp, 32, 64); ln += __shfl_xor(ln, 32, 64);
    if (lane == 0) { s[wid] = lp; s[8 + wid] = ln; }
    __syncthreads();
    if (threadIdx.x == 0) atomicAdd(&lossacc[0], s[0] + s[1] + s[2] + s[3]);
    if (threadIdx.x == 1) atomicAdd(&lossacc[1], s[8] + s[9] + s[10] + s[11]);
}

__global__ void finalize_kernel(const float* __restrict__ lossacc,
                                float* __restrict__ out, float invN) {
    out[0] = (lossacc[0] + lossacc[1]) * invN;
}

// ---------------------------------------------------------------------------
extern "C" void kernel_launch(void* const* d_in, const int* in_sizes, int n_in,
                              void* d_out, int out_size, void* d_ws, size_t ws_size,
                              hipStream_t stream) {
    const float* x    = (const float*)d_in[0];
    const float* W1   = (const float*)d_in[1];
    const float* b1   = (const float*)d_in[2];
    const float* W2   = (const float*)d_in[3];
    const float* b2   = (const float*)d_in[4];
    const float* Wdgi = (const float*)d_in[5];
    const int*   edge = (const int*)d_in[6];
    const int*   perm = (const int*)d_in[7];

    const int N = in_sizes[7];
    const int E = in_sizes[6] / 2;
    const int* row = edge;
    const int* col = edge + E;
    const int nb = (N + NPB - 1) >> NB_SHIFT;

    char* wsb = (char*)d_ws;
    size_t woff = 0;
    auto alloc = [&](size_t bytes) -> void* {
        void* p = wsb + woff;
        woff = (woff + bytes + 255) & ~(size_t)255;
        return p;
    };
    int*    bucket   = (int*)  alloc((size_t)nb * BINREGION * 4);  // 9.6 MB
    uint*   bins     = (uint*) alloc((size_t)nb * BINCAP * 4);     // 8 MB
    int*    bincnt   = (int*)  alloc((size_t)nb * 4);
    int*    cnt      = (int*)  alloc((size_t)N * 4);
    int*    off      = (int*)  alloc((size_t)N * 4);
    ushort* G        = (ushort*)alloc((size_t)N * 64 * 2);         // fp8-packed, 12.8 MB
    uint*   H        = (uint*) alloc((size_t)N * 64 * 4);          // bf16-packed, 25.6 MB
    float*  colpart  = (float*)alloc((size_t)GG * 64 * 4);
    float*  colpart2 = (float*)alloc((size_t)(GG / RB) * 64 * 4);
    float*  wsv      = (float*)alloc(64 * 4);
    float*  lossacc  = (float*)alloc(2 * 4);

    hipMemsetAsync(bincnt, 0, (size_t)nb * 4, stream);
    hipMemsetAsync(lossacc, 0, 8, stream);

    const int nchunks = (E + PCHUNK - 1) / PCHUNK;
    partition_edges<<<nchunks, 256, 0, stream>>>(row, col, bins, bincnt, E, nb);
    place_lds<<<nb, 256, 0, stream>>>(bins, bincnt, bucket, off, cnt, N);

    // layer 1: G = fp8((X @ W1) * dis) both branches, aggregate+relu -> H
    gemm1_mfma<<<1024, 256, 0, stream>>>(x, W1, perm, cnt, G, N);
    conv_packed<0><<<GG, 256, 0, stream>>>(G, bucket, off, cnt, b1, H, nullptr, N);
    // layer 2: G = fp8((H @ W2) * dis), aggregate -> z (in H) + colpart
    gemm2_mfma<<<1024, 256, 0, stream>>>(H, W2, cnt, G, N);
    conv_packed<1><<<GG, 256, 0, stream>>>(G, bucket, off, cnt, b2, H, colpart, N);

    colreduce_kernel<<<GG / RB, 256, 0, stream>>>(colpart, colpart2);
    summary_kernel<<<1, 256, 0, stream>>>(colpart2, Wdgi, wsv, GG / RB, 1.0f / N);
    loss4_kernel<<<1024, 256, 0, stream>>>(H, wsv, lossacc, N);
    finalize_kernel<<<1, 1, 0, stream>>>(lossacc, (float*)d_out, 1.0f / N);
}

// Round 14
// 220.850 us; speedup vs baseline: 1.1014x; 1.1014x over previous
//
#include <hip/hip_runtime.h>
#include <hip/hip_bf16.h>
#include <math.h>

#define GG 2048          // conv grid (colpart rows)
#define RB 32            // colpart rows per stage-A block
#define NB_SHIFT 9       // 512 nodes per bin
#define NPB 512
#define BINCAP 10240     // edges per bin (mean 8192, 6-sigma ~8740)
#define BINREGION 12288  // padded words per bin bucket region (48 KB LDS window)
#define PCHUNK 8192      // edges per partition chunk

typedef __hip_bfloat16 bf16;
typedef unsigned int uint;
typedef unsigned short ushort;
typedef unsigned char uchar;
typedef short bf16x8 __attribute__((ext_vector_type(8)));
typedef float f32x4 __attribute__((ext_vector_type(4)));
typedef float f32x2 __attribute__((ext_vector_type(2)));

__device__ __forceinline__ bf16  f2b(float x) { return __float2bfloat16(x); }
__device__ __forceinline__ short f2bs(float x) {
    bf16 b = __float2bfloat16(x);
    return *reinterpret_cast<short*>(&b);
}
// bf16-packed pos/neg (conv outputs H, z)
__device__ __forceinline__ float posf(uint u) { return __uint_as_float(u << 16); }
__device__ __forceinline__ float negf(uint u) { return __uint_as_float(u & 0xFFFF0000u); }
__device__ __forceinline__ uint  packbf(float p, float n) {
    bf16 bp = f2b(p), bn = f2b(n);
    ushort up = *reinterpret_cast<ushort*>(&bp);
    ushort un = *reinterpret_cast<ushort*>(&bn);
    return (uint)up | ((uint)un << 16);
}
// fp8 e4m3-packed pos/neg (conv inputs G): byte0=pos, byte1=neg
__device__ __forceinline__ ushort packfp8(float p, float n) {
    return (ushort)__builtin_amdgcn_cvt_pk_fp8_f32(p, n, 0, false);
}
__device__ __forceinline__ f32x2 unpackfp8(uint u) {
    return __builtin_amdgcn_cvt_pk_f32_fp8((int)u, false);
}

// ---- P1: partition edges into bins of 512 nodes; packed u = (r<<9)|(c&511).
__global__ __launch_bounds__(256) void partition_edges(
        const int* __restrict__ row, const int* __restrict__ col,
        uint* __restrict__ bins, int* __restrict__ bincnt, int E, int nb) {
    __shared__ int lcnt[256];
    __shared__ int lbase[256];
    for (int chunk = blockIdx.x * PCHUNK; chunk < E; chunk += gridDim.x * PCHUNK) {
        int end = chunk + PCHUNK < E ? chunk + PCHUNK : E;
        if (threadIdx.x < nb) lcnt[threadIdx.x] = 0;
        __syncthreads();
        for (int e = chunk + threadIdx.x; e < end; e += 256)
            atomicAdd(&lcnt[col[e] >> NB_SHIFT], 1);
        __syncthreads();
        if (threadIdx.x < nb) {
            lbase[threadIdx.x] = atomicAdd(&bincnt[threadIdx.x], lcnt[threadIdx.x]);
            lcnt[threadIdx.x] = 0;
        }
        __syncthreads();
        for (int e = chunk + threadIdx.x; e < end; e += 256) {
            int c = col[e], r = row[e];
            int g = c >> NB_SHIFT;
            int dst = lbase[g] + atomicAdd(&lcnt[g], 1);
            if (dst < BINCAP)
                bins[(size_t)g * BINCAP + dst] = ((uint)r << NB_SHIFT) | (uint)(c & (NPB - 1));
        }
        __syncthreads();
    }
}

// ---- P2: one block per bin. LDS hist -> cnt; LDS padded prefix -> off;
// LDS-window scatter; coalesced int4 write-out. ------------------------------
__global__ __launch_bounds__(256) void place_lds(
        const uint* __restrict__ bins, const int* __restrict__ bincnt,
        int* __restrict__ bucket, int* __restrict__ off, int* __restrict__ cnt,
        int N) {
    __shared__ int lcnt[NPB];
    __shared__ int s[NPB];
    __shared__ int win[BINREGION];
    int b  = blockIdx.x;
    int lo = b << NB_SHIFT;
    int base = b * BINREGION;
    int ne = bincnt[b];
    if (ne > BINCAP) ne = BINCAP;
    const uint* be = bins + (size_t)b * BINCAP;
    for (int i = threadIdx.x; i < NPB; i += 256) lcnt[i] = 0;
    __syncthreads();
    for (int i = threadIdx.x; i < ne; i += 256)
        atomicAdd(&lcnt[be[i] & (NPB - 1)], 1);
    __syncthreads();
    int i0 = threadIdx.x, i1 = threadIdx.x + 256;
    s[i0] = (lcnt[i0] + 3) & ~3;
    s[i1] = (lcnt[i1] + 3) & ~3;
    __syncthreads();
    for (int st = 1; st < NPB; st <<= 1) {
        int v0 = i0 >= st ? s[i0 - st] : 0;
        int v1 = i1 >= st ? s[i1 - st] : 0;
        __syncthreads();
        s[i0] += v0; s[i1] += v1;
        __syncthreads();
    }
    for (int i = threadIdx.x; i < NPB; i += 256) {
        int v = lo + i;
        int pc = (lcnt[i] + 3) & ~3;
        int start = s[i] - pc;
        if (v < N) { off[v] = base + start; cnt[v] = lcnt[i]; }
        lcnt[i] = start;
    }
    __syncthreads();
    for (int i = threadIdx.x; i < ne; i += 256) {
        uint u = be[i];
        int slot = atomicAdd(&lcnt[u & (NPB - 1)], 1);
        if (slot < BINREGION) win[slot] = (int)(u >> NB_SHIFT);
    }
    __syncthreads();
    int wsize = s[NPB - 1];
    if (wsize > BINREGION) wsize = BINREGION;
    for (int i = threadIdx.x * 4; i < wsize; i += 1024)
        *(int4*)&bucket[base + i] = *(const int4*)&win[i];
}

// ---- layer-1 GEMM via MFMA; fp8-packed output -----------------------------
__global__ __launch_bounds__(256) void gemm1_mfma(
        const float* __restrict__ X, const float* __restrict__ W,
        const int* __restrict__ perm, const int* __restrict__ cnt,
        ushort* __restrict__ out, int n) {
    int lane = threadIdx.x & 63, wid = threadIdx.x >> 6;
    int l15 = lane & 15, lg = lane >> 4;
    bf16x8 bfr[2][4];
#pragma unroll
    for (int kt = 0; kt < 2; kt++)
#pragma unroll
        for (int nt = 0; nt < 4; nt++)
#pragma unroll
            for (int i = 0; i < 8; i++)
                bfr[kt][nt][i] = f2bs(W[(kt * 32 + lg * 8 + i) * 64 + nt * 16 + l15]);
    int ntiles = (n + 15) >> 4;
    for (int t = blockIdx.x * 4 + wid; t < ntiles; t += gridDim.x * 4) {
        int rowA = t * 16 + l15;
        if (rowA >= n) rowA = n - 1;
        int prow = perm[rowA];
        const float4* xp = (const float4*)(X + (size_t)rowA * 64);
        const float4* xn = (const float4*)(X + (size_t)prow * 64);
        bf16x8 ap[2], an[2];
#pragma unroll
        for (int kt = 0; kt < 2; kt++) {
            float4 p0 = xp[kt * 8 + lg * 2], p1 = xp[kt * 8 + lg * 2 + 1];
            float4 n0 = xn[kt * 8 + lg * 2], n1 = xn[kt * 8 + lg * 2 + 1];
            ap[kt][0] = f2bs(p0.x); ap[kt][1] = f2bs(p0.y);
            ap[kt][2] = f2bs(p0.z); ap[kt][3] = f2bs(p0.w);
            ap[kt][4] = f2bs(p1.x); ap[kt][5] = f2bs(p1.y);
            ap[kt][6] = f2bs(p1.z); ap[kt][7] = f2bs(p1.w);
            an[kt][0] = f2bs(n0.x); an[kt][1] = f2bs(n0.y);
            an[kt][2] = f2bs(n0.z); an[kt][3] = f2bs(n0.w);
            an[kt][4] = f2bs(n1.x); an[kt][5] = f2bs(n1.y);
            an[kt][6] = f2bs(n1.z); an[kt][7] = f2bs(n1.w);
        }
        f32x4 accp[4], accn[4];
#pragma unroll
        for (int nt = 0; nt < 4; nt++) { accp[nt] = (f32x4)0.f; accn[nt] = (f32x4)0.f; }
#pragma unroll
        for (int nt = 0; nt < 4; nt++) {
            accp[nt] = __builtin_amdgcn_mfma_f32_16x16x32_bf16(ap[0], bfr[0][nt], accp[nt], 0, 0, 0);
            accp[nt] = __builtin_amdgcn_mfma_f32_16x16x32_bf16(ap[1], bfr[1][nt], accp[nt], 0, 0, 0);
            accn[nt] = __builtin_amdgcn_mfma_f32_16x16x32_bf16(an[0], bfr[0][nt], accn[nt], 0, 0, 0);
            accn[nt] = __builtin_amdgcn_mfma_f32_16x16x32_bf16(an[1], bfr[1][nt], accn[nt], 0, 0, 0);
        }
        float dvr[4];
#pragma unroll
        for (int reg = 0; reg < 4; reg++) {
            int node = t * 16 + lg * 4 + reg;
            dvr[reg] = node < n ? rsqrtf((float)cnt[node] + 1.0f) : 0.f;
        }
#pragma unroll
        for (int nt = 0; nt < 4; nt++)
#pragma unroll
            for (int reg = 0; reg < 4; reg++) {
                int node = t * 16 + lg * 4 + reg;
                if (node < n)
                    out[(size_t)node * 64 + nt * 16 + l15] =
                        packfp8(accp[nt][reg] * dvr[reg], accn[nt][reg] * dvr[reg]);
            }
    }
}

// ---- layer-2 GEMM via MFMA, bf16-packed in, fp8-packed out -----------------
__global__ __launch_bounds__(256) void gemm2_mfma(
        const uint* __restrict__ H, const float* __restrict__ W,
        const int* __restrict__ cnt, ushort* __restrict__ out, int n) {
    int lane = threadIdx.x & 63, wid = threadIdx.x >> 6;
    int l15 = lane & 15, lg = lane >> 4;
    bf16x8 bfr[2][4];
#pragma unroll
    for (int kt = 0; kt < 2; kt++)
#pragma unroll
        for (int nt = 0; nt < 4; nt++)
#pragma unroll
            for (int i = 0; i < 8; i++)
                bfr[kt][nt][i] = f2bs(W[(kt * 32 + lg * 8 + i) * 64 + nt * 16 + l15]);
    int ntiles = (n + 15) >> 4;
    for (int t = blockIdx.x * 4 + wid; t < ntiles; t += gridDim.x * 4) {
        int rowA = t * 16 + l15;
        if (rowA >= n) rowA = n - 1;
        const uint4* h = (const uint4*)(H + (size_t)rowA * 64);
        bf16x8 ap[2], an[2];
#pragma unroll
        for (int kt = 0; kt < 2; kt++) {
            uint4 u0 = h[kt * 8 + lg * 2], u1 = h[kt * 8 + lg * 2 + 1];
            uint uu[8] = {u0.x, u0.y, u0.z, u0.w, u1.x, u1.y, u1.z, u1.w};
#pragma unroll
            for (int i = 0; i < 8; i++) {
                ap[kt][i] = (short)(uu[i] & 0xFFFFu);
                an[kt][i] = (short)(uu[i] >> 16);
            }
        }
        f32x4 accp[4], accn[4];
#pragma unroll
        for (int nt = 0; nt < 4; nt++) { accp[nt] = (f32x4)0.f; accn[nt] = (f32x4)0.f; }
#pragma unroll
        for (int nt = 0; nt < 4; nt++) {
            accp[nt] = __builtin_amdgcn_mfma_f32_16x16x32_bf16(ap[0], bfr[0][nt], accp[nt], 0, 0, 0);
            accp[nt] = __builtin_amdgcn_mfma_f32_16x16x32_bf16(ap[1], bfr[1][nt], accp[nt], 0, 0, 0);
            accn[nt] = __builtin_amdgcn_mfma_f32_16x16x32_bf16(an[0], bfr[0][nt], accn[nt], 0, 0, 0);
            accn[nt] = __builtin_amdgcn_mfma_f32_16x16x32_bf16(an[1], bfr[1][nt], accn[nt], 0, 0, 0);
        }
        float dvr[4];
#pragma unroll
        for (int reg = 0; reg < 4; reg++) {
            int node = t * 16 + lg * 4 + reg;
            dvr[reg] = node < n ? rsqrtf((float)cnt[node] + 1.0f) : 0.f;
        }
#pragma unroll
        for (int nt = 0; nt < 4; nt++)
#pragma unroll
            for (int reg = 0; reg < 4; reg++) {
                int node = t * 16 + lg * 4 + reg;
                if (node < n)
                    out[(size_t)node * 64 + nt * 16 + l15] =
                        packfp8(accp[nt][reg] * dvr[reg], accn[nt][reg] * dvr[reg]);
            }
    }
}

// ---- fused GCN aggregation (R12 layout): fp8 gather in, bf16-packed out ---
// wave per node, lane = dim. Byte-offset addressing: one lshl_add per gather.
template <int MODE>
__global__ __launch_bounds__(256) void conv_packed(
        const ushort* __restrict__ g, const int* __restrict__ bucket,
        const int* __restrict__ off, const int* __restrict__ cnt,
        const float* __restrict__ bias,
        uint* __restrict__ out, float* __restrict__ colpart, int n) {
    int lane = threadIdx.x & 63, wid = threadIdx.x >> 6;
    const uchar* gb = (const uchar*)g;
    uint l2 = (uint)lane * 2;
    __shared__ float s[256];
    float colp  = 0.f;
    float blane = bias[lane];
    int wstart = blockIdx.x * 4 + wid, wstride = gridDim.x * 4;
    for (int v = wstart; v < n; v += wstride) {
        int c = cnt[v];
        float dv = rsqrtf((float)c + 1.0f);
        f32x2 sv = unpackfp8(*(const ushort*)(gb + (((uint)v << 7) + l2)));
        float a0p = sv.x, a1p = 0.f, a2p = 0.f, a3p = 0.f;   // self in a0
        float a0n = sv.y, a1n = 0.f, a2n = 0.f, a3n = 0.f;
        const int*  bk  = bucket + off[v];
        const int4* bk4 = (const int4*)bk;
        int nq8 = c >> 3;
        for (int q = 0; q < nq8; q++) {
            int4 ra = bk4[2 * q], rb = bk4[2 * q + 1];
            uint u0 = *(const ushort*)(gb + (((uint)ra.x << 7) + l2));
            uint u1 = *(const ushort*)(gb + (((uint)ra.y << 7) + l2));
            uint u2 = *(const ushort*)(gb + (((uint)ra.z << 7) + l2));
            uint u3 = *(const ushort*)(gb + (((uint)ra.w << 7) + l2));
            uint u4 = *(const ushort*)(gb + (((uint)rb.x << 7) + l2));
            uint u5 = *(const ushort*)(gb + (((uint)rb.y << 7) + l2));
            uint u6 = *(const ushort*)(gb + (((uint)rb.z << 7) + l2));
            uint u7 = *(const ushort*)(gb + (((uint)rb.w << 7) + l2));
            f32x2 d0 = unpackfp8(u0), d1 = unpackfp8(u1);
            f32x2 d2 = unpackfp8(u2), d3 = unpackfp8(u3);
            f32x2 d4 = unpackfp8(u4), d5 = unpackfp8(u5);
            f32x2 d6 = unpackfp8(u6), d7 = unpackfp8(u7);
            a0p += d0.x + d4.x; a0n += d0.y + d4.y;
            a1p += d1.x + d5.x; a1n += d1.y + d5.y;
            a2p += d2.x + d6.x; a2n += d2.y + d6.y;
            a3p += d3.x + d7.x; a3n += d3.y + d7.y;
        }
        int i = nq8 << 3;
        if (c - i >= 4) {
            int4 r = bk4[i >> 2];
            f32x2 d0 = unpackfp8(*(const ushort*)(gb + (((uint)r.x << 7) + l2)));
            f32x2 d1 = unpackfp8(*(const ushort*)(gb + (((uint)r.y << 7) + l2)));
            f32x2 d2 = unpackfp8(*(const ushort*)(gb + (((uint)r.z << 7) + l2)));
            f32x2 d3 = unpackfp8(*(const ushort*)(gb + (((uint)r.w << 7) + l2)));
            a0p += d0.x; a0n += d0.y;
            a1p += d1.x; a1n += d1.y;
            a2p += d2.x; a2n += d2.y;
            a3p += d3.x; a3n += d3.y;
            i += 4;
        }
        for (; i < c; i++) {
            f32x2 d = unpackfp8(*(const ushort*)(gb + (((uint)bk[i] << 7) + l2)));
            a0p += d.x;
            a0n += d.y;
        }
        float sp = (a0p + a1p) + (a2p + a3p);
        float sn = (a0n + a1n) + (a2n + a3n);
        float rp = fmaf(dv, sp, blane);
        float rn = fmaf(dv, sn, blane);
        size_t vo = (size_t)v * 64 + lane;
        if (MODE == 0) {
            out[vo] = packbf(fmaxf(rp, 0.f), fmaxf(rn, 0.f));
        } else {
            out[vo] = packbf(rp, rn);
            colp += rp;
        }
    }
    if (MODE == 1) {
        s[wid * 64 + lane] = colp;
        __syncthreads();
        if (wid == 0) {
            float t = s[lane] + s[64 + lane] + s[128 + lane] + s[192 + lane];
            colpart[(size_t)blockIdx.x * 64 + lane] = t;
        }
    }
}

// ---- stage A: sum RB colpart rows per block -> colpart2 --------------------
__global__ __launch_bounds__(256) void colreduce_kernel(
        const float* __restrict__ colpart, float* __restrict__ colpart2) {
    int lane = threadIdx.x & 63, w = threadIdx.x >> 6;
    __shared__ float s4[4][64];
    float t = 0.f;
    int base = blockIdx.x * RB;
    for (int g = w; g < RB; g += 4) t += colpart[(size_t)(base + g) * 64 + lane];
    s4[w][lane] = t;
    __syncthreads();
    if (w == 0)
        colpart2[(size_t)blockIdx.x * 64 + lane] =
            s4[0][lane] + s4[1][lane] + s4[2][lane] + s4[3][lane];
}

// ---- summary + ws = W_dgi @ sigmoid(mean(pos_z)) ---------------------------
__global__ void summary_kernel(const float* __restrict__ colpart,
                               const float* __restrict__ Wdgi,
                               float* __restrict__ wsv, int G, float invN) {
    __shared__ float sm[64];
    __shared__ float s4[4][64];
    int lane = threadIdx.x & 63, w = threadIdx.x >> 6;
    float t = 0.f;
    for (int g = w; g < G; g += 4) t += colpart[(size_t)g * 64 + lane];
    s4[w][lane] = t;
    __syncthreads();
    if (w == 0) {
        t = s4[0][lane] + s4[1][lane] + s4[2][lane] + s4[3][lane];
        sm[lane] = 1.f / (1.f + expf(-t * invN));
    }
    __syncthreads();
    if (threadIdx.x < 64) {
        float a = 0.f;
        for (int j = 0; j < 64; j++) a += Wdgi[threadIdx.x * 64 + j] * sm[j];
        wsv[threadIdx.x] = a;
    }
}

// ---- both losses: 16-lane group per node, 4 nodes per wave-iteration -------
__global__ __launch_bounds__(256) void loss4_kernel(
        const uint* __restrict__ z, const float* __restrict__ wsv,
        float* __restrict__ lossacc, int n) {
    int lane = threadIdx.x & 63, wid = threadIdx.x >> 6;
    int sub = lane >> 4, dch = lane & 15;
    __shared__ float s[16];
    float w0 = wsv[dch * 4], w1 = wsv[dch * 4 + 1];
    float w2 = wsv[dch * 4 + 2], w3 = wsv[dch * 4 + 3];
    float lp = 0.f, ln = 0.f;
    int nq = (n + 3) >> 2;
    for (int qi = blockIdx.x * 4 + wid; qi < nq; qi += gridDim.x * 4) {
        int v = qi * 4 + sub;
        float p = 0.f, q = 0.f;
        if (v < n) {
            uint4 u = *(const uint4*)(z + (size_t)v * 64 + dch * 4);
            p = posf(u.x) * w0 + posf(u.y) * w1 + posf(u.z) * w2 + posf(u.w) * w3;
            q = negf(u.x) * w0 + negf(u.y) * w1 + negf(u.z) * w2 + negf(u.w) * w3;
        }
        for (int o = 1; o < 16; o <<= 1) {
            p += __shfl_xor(p, o, 64);
            q += __shfl_xor(q, o, 64);
        }
        if (dch == 0 && v < n) {
            lp += -logf(1.f / (1.f + expf(-p)) + 1e-15f);   // -log(sigmoid(p)+eps)
            ln += -logf(1.f / (1.f + expf( q)) + 1e-15f);   // -log(1-sigmoid(q)+eps)
        }
    }
    lp += __shfl_xor(lp, 16, 64); ln += __shfl_xor(ln, 16, 64);
    lp += __shfl_xor(lp, 32, 64); ln += __shfl_xor(ln, 32, 64);
    if (lane == 0) { s[wid] = lp; s[8 + wid] = ln; }
    __syncthreads();
    if (threadIdx.x == 0) atomicAdd(&lossacc[0], s[0] + s[1] + s[2] + s[3]);
    if (threadIdx.x == 1) atomicAdd(&lossacc[1], s[8] + s[9] + s[10] + s[11]);
}

__global__ void finalize_kernel(const float* __restrict__ lossacc,
                                float* __restrict__ out, float invN) {
    out[0] = (lossacc[0] + lossacc[1]) * invN;
}

// ---------------------------------------------------------------------------
extern "C" void kernel_launch(void* const* d_in, const int* in_sizes, int n_in,
                              void* d_out, int out_size, void* d_ws, size_t ws_size,
                              hipStream_t stream) {
    const float* x    = (const float*)d_in[0];
    const float* W1   = (const float*)d_in[1];
    const float* b1   = (const float*)d_in[2];
    const float* W2   = (const float*)d_in[3];
    const float* b2   = (const float*)d_in[4];
    const float* Wdgi = (const float*)d_in[5];
    const int*   edge = (const int*)d_in[6];
    const int*   perm = (const int*)d_in[7];

    const int N = in_sizes[7];
    const int E = in_sizes[6] / 2;
    const int* row = edge;
    const int* col = edge + E;
    const int nb = (N + NPB - 1) >> NB_SHIFT;

    char* wsb = (char*)d_ws;
    size_t woff = 0;
    auto alloc = [&](size_t bytes) -> void* {
        void* p = wsb + woff;
        woff = (woff + bytes + 255) & ~(size_t)255;
        return p;
    };
    int*    bucket   = (int*)  alloc((size_t)nb * BINREGION * 4);  // 9.6 MB
    uint*   bins     = (uint*) alloc((size_t)nb * BINCAP * 4);     // 8 MB
    int*    bincnt   = (int*)  alloc((size_t)nb * 4);
    int*    cnt      = (int*)  alloc((size_t)N * 4);
    int*    off      = (int*)  alloc((size_t)N * 4);
    ushort* G        = (ushort*)alloc((size_t)N * 64 * 2);         // fp8-packed, 12.8 MB
    uint*   H        = (uint*) alloc((size_t)N * 64 * 4);          // bf16-packed, 25.6 MB
    float*  colpart  = (float*)alloc((size_t)GG * 64 * 4);
    float*  colpart2 = (float*)alloc((size_t)(GG / RB) * 64 * 4);
    float*  wsv      = (float*)alloc(64 * 4);
    float*  lossacc  = (float*)alloc(2 * 4);

    hipMemsetAsync(bincnt, 0, (size_t)nb * 4, stream);
    hipMemsetAsync(lossacc, 0, 8, stream);

    const int nchunks = (E + PCHUNK - 1) / PCHUNK;
    partition_edges<<<nchunks, 256, 0, stream>>>(row, col, bins, bincnt, E, nb);
    place_lds<<<nb, 256, 0, stream>>>(bins, bincnt, bucket, off, cnt, N);

    // layer 1: G = fp8((X @ W1) * dis) both branches, aggregate+relu -> H
    gemm1_mfma<<<1024, 256, 0, stream>>>(x, W1, perm, cnt, G, N);
    conv_packed<0><<<GG, 256, 0, stream>>>(G, bucket, off, cnt, b1, H, nullptr, N);
    // layer 2: G = fp8((H @ W2) * dis), aggregate -> z (in H) + colpart
    gemm2_mfma<<<1024, 256, 0, stream>>>(H, W2, cnt, G, N);
    conv_packed<1><<<GG, 256, 0, stream>>>(G, bucket, off, cnt, b2, H, colpart, N);

    colreduce_kernel<<<GG / RB, 256, 0, stream>>>(colpart, colpart2);
    summary_kernel<<<1, 256, 0, stream>>>(colpart2, Wdgi, wsv, GG / RB, 1.0f / N);
    loss4_kernel<<<1024, 256, 0, stream>>>(H, wsv, lossacc, N);
    finalize_kernel<<<1, 1, 0, stream>>>(lossacc, (float*)d_out, 1.0f / N);
}

// Round 15
// 218.377 us; speedup vs baseline: 1.1139x; 1.0113x over previous
//
#include <hip/hip_runtime.h>
#include <hip/hip_bf16.h>
#include <math.h>

#define GG 2048          // conv grid (colpart rows)
#define RB 32            // colpart rows per stage-A block
#define NB_SHIFT 9       // 512 nodes per bin
#define NPB 512
#define BINCAP 10240     // edges per bin (mean 8192, 6-sigma ~8740)
#define BINREGION 12288  // padded words per bin bucket region (48 KB LDS window)
#define PCHUNK 2048      // edges per partition chunk (782 blocks for E=1.6M)

typedef __hip_bfloat16 bf16;
typedef unsigned int uint;
typedef unsigned short ushort;
typedef unsigned char uchar;
typedef short bf16x8 __attribute__((ext_vector_type(8)));
typedef float f32x4 __attribute__((ext_vector_type(4)));
typedef float f32x2 __attribute__((ext_vector_type(2)));

__device__ __forceinline__ bf16  f2b(float x) { return __float2bfloat16(x); }
__device__ __forceinline__ short f2bs(float x) {
    bf16 b = __float2bfloat16(x);
    return *reinterpret_cast<short*>(&b);
}
// fp8 e4m3-packed pos/neg (all intermediates): byte0=pos, byte1=neg per dim
__device__ __forceinline__ ushort packfp8(float p, float n) {
    return (ushort)__builtin_amdgcn_cvt_pk_fp8_f32(p, n, 0, false);
}
__device__ __forceinline__ f32x2 unpackfp8(uint u) {       // low 16 bits
    return __builtin_amdgcn_cvt_pk_f32_fp8((int)u, false);
}
__device__ __forceinline__ f32x2 unpackfp8_hi(uint u) {    // high 16 bits
    return __builtin_amdgcn_cvt_pk_f32_fp8((int)u, true);
}

// ---- P1: partition edges into bins of 512 nodes; packed u = (r<<9)|(c&511).
__global__ __launch_bounds__(256) void partition_edges(
        const int* __restrict__ row, const int* __restrict__ col,
        uint* __restrict__ bins, int* __restrict__ bincnt, int E, int nb) {
    __shared__ int lcnt[256];
    __shared__ int lbase[256];
    for (int chunk = blockIdx.x * PCHUNK; chunk < E; chunk += gridDim.x * PCHUNK) {
        int end = chunk + PCHUNK < E ? chunk + PCHUNK : E;
        if (threadIdx.x < nb) lcnt[threadIdx.x] = 0;
        __syncthreads();
        for (int e = chunk + threadIdx.x; e < end; e += 256)
            atomicAdd(&lcnt[col[e] >> NB_SHIFT], 1);
        __syncthreads();
        if (threadIdx.x < nb) {
            lbase[threadIdx.x] = atomicAdd(&bincnt[threadIdx.x], lcnt[threadIdx.x]);
            lcnt[threadIdx.x] = 0;
        }
        __syncthreads();
        for (int e = chunk + threadIdx.x; e < end; e += 256) {
            int c = col[e], r = row[e];
            int g = c >> NB_SHIFT;
            int dst = lbase[g] + atomicAdd(&lcnt[g], 1);
            if (dst < BINCAP)
                bins[(size_t)g * BINCAP + dst] = ((uint)r << NB_SHIFT) | (uint)(c & (NPB - 1));
        }
        __syncthreads();
    }
}

// ---- P2: one block per bin. LDS hist -> cnt; LDS padded prefix -> off;
// LDS-window scatter; coalesced int4 write-out. ------------------------------
__global__ __launch_bounds__(256) void place_lds(
        const uint* __restrict__ bins, const int* __restrict__ bincnt,
        int* __restrict__ bucket, int* __restrict__ off, int* __restrict__ cnt,
        int N) {
    __shared__ int lcnt[NPB];
    __shared__ int s[NPB];
    __shared__ int win[BINREGION];
    int b  = blockIdx.x;
    int lo = b << NB_SHIFT;
    int base = b * BINREGION;
    int ne = bincnt[b];
    if (ne > BINCAP) ne = BINCAP;
    const uint* be = bins + (size_t)b * BINCAP;
    for (int i = threadIdx.x; i < NPB; i += 256) lcnt[i] = 0;
    __syncthreads();
    for (int i = threadIdx.x; i < ne; i += 256)
        atomicAdd(&lcnt[be[i] & (NPB - 1)], 1);
    __syncthreads();
    int i0 = threadIdx.x, i1 = threadIdx.x + 256;
    s[i0] = (lcnt[i0] + 3) & ~3;
    s[i1] = (lcnt[i1] + 3) & ~3;
    __syncthreads();
    for (int st = 1; st < NPB; st <<= 1) {
        int v0 = i0 >= st ? s[i0 - st] : 0;
        int v1 = i1 >= st ? s[i1 - st] : 0;
        __syncthreads();
        s[i0] += v0; s[i1] += v1;
        __syncthreads();
    }
    for (int i = threadIdx.x; i < NPB; i += 256) {
        int v = lo + i;
        int pc = (lcnt[i] + 3) & ~3;
        int start = s[i] - pc;
        if (v < N) { off[v] = base + start; cnt[v] = lcnt[i]; }
        lcnt[i] = start;
    }
    __syncthreads();
    for (int i = threadIdx.x; i < ne; i += 256) {
        uint u = be[i];
        int slot = atomicAdd(&lcnt[u & (NPB - 1)], 1);
        if (slot < BINREGION) win[slot] = (int)(u >> NB_SHIFT);
    }
    __syncthreads();
    int wsize = s[NPB - 1];
    if (wsize > BINREGION) wsize = BINREGION;
    for (int i = threadIdx.x * 4; i < wsize; i += 1024)
        *(int4*)&bucket[base + i] = *(const int4*)&win[i];
}

// ---- layer-1 GEMM via MFMA; fp8-packed output -----------------------------
__global__ __launch_bounds__(256) void gemm1_mfma(
        const float* __restrict__ X, const float* __restrict__ W,
        const int* __restrict__ perm, const int* __restrict__ cnt,
        ushort* __restrict__ out, int n) {
    int lane = threadIdx.x & 63, wid = threadIdx.x >> 6;
    int l15 = lane & 15, lg = lane >> 4;
    bf16x8 bfr[2][4];
#pragma unroll
    for (int kt = 0; kt < 2; kt++)
#pragma unroll
        for (int nt = 0; nt < 4; nt++)
#pragma unroll
            for (int i = 0; i < 8; i++)
                bfr[kt][nt][i] = f2bs(W[(kt * 32 + lg * 8 + i) * 64 + nt * 16 + l15]);
    int ntiles = (n + 15) >> 4;
    for (int t = blockIdx.x * 4 + wid; t < ntiles; t += gridDim.x * 4) {
        int rowA = t * 16 + l15;
        if (rowA >= n) rowA = n - 1;
        int prow = perm[rowA];
        const float4* xp = (const float4*)(X + (size_t)rowA * 64);
        const float4* xn = (const float4*)(X + (size_t)prow * 64);
        bf16x8 ap[2], an[2];
#pragma unroll
        for (int kt = 0; kt < 2; kt++) {
            float4 p0 = xp[kt * 8 + lg * 2], p1 = xp[kt * 8 + lg * 2 + 1];
            float4 n0 = xn[kt * 8 + lg * 2], n1 = xn[kt * 8 + lg * 2 + 1];
            ap[kt][0] = f2bs(p0.x); ap[kt][1] = f2bs(p0.y);
            ap[kt][2] = f2bs(p0.z); ap[kt][3] = f2bs(p0.w);
            ap[kt][4] = f2bs(p1.x); ap[kt][5] = f2bs(p1.y);
            ap[kt][6] = f2bs(p1.z); ap[kt][7] = f2bs(p1.w);
            an[kt][0] = f2bs(n0.x); an[kt][1] = f2bs(n0.y);
            an[kt][2] = f2bs(n0.z); an[kt][3] = f2bs(n0.w);
            an[kt][4] = f2bs(n1.x); an[kt][5] = f2bs(n1.y);
            an[kt][6] = f2bs(n1.z); an[kt][7] = f2bs(n1.w);
        }
        f32x4 accp[4], accn[4];
#pragma unroll
        for (int nt = 0; nt < 4; nt++) { accp[nt] = (f32x4)0.f; accn[nt] = (f32x4)0.f; }
#pragma unroll
        for (int nt = 0; nt < 4; nt++) {
            accp[nt] = __builtin_amdgcn_mfma_f32_16x16x32_bf16(ap[0], bfr[0][nt], accp[nt], 0, 0, 0);
            accp[nt] = __builtin_amdgcn_mfma_f32_16x16x32_bf16(ap[1], bfr[1][nt], accp[nt], 0, 0, 0);
            accn[nt] = __builtin_amdgcn_mfma_f32_16x16x32_bf16(an[0], bfr[0][nt], accn[nt], 0, 0, 0);
            accn[nt] = __builtin_amdgcn_mfma_f32_16x16x32_bf16(an[1], bfr[1][nt], accn[nt], 0, 0, 0);
        }
        float dvr[4];
#pragma unroll
        for (int reg = 0; reg < 4; reg++) {
            int node = t * 16 + lg * 4 + reg;
            dvr[reg] = node < n ? rsqrtf((float)cnt[node] + 1.0f) : 0.f;
        }
#pragma unroll
        for (int nt = 0; nt < 4; nt++)
#pragma unroll
            for (int reg = 0; reg < 4; reg++) {
                int node = t * 16 + lg * 4 + reg;
                if (node < n)
                    out[(size_t)node * 64 + nt * 16 + l15] =
                        packfp8(accp[nt][reg] * dvr[reg], accn[nt][reg] * dvr[reg]);
            }
    }
}

// ---- layer-2 GEMM via MFMA, fp8-packed in (unpack->bf16), fp8 out ---------
__global__ __launch_bounds__(256) void gemm2_mfma(
        const ushort* __restrict__ H, const float* __restrict__ W,
        const int* __restrict__ cnt, ushort* __restrict__ out, int n) {
    int lane = threadIdx.x & 63, wid = threadIdx.x >> 6;
    int l15 = lane & 15, lg = lane >> 4;
    bf16x8 bfr[2][4];
#pragma unroll
    for (int kt = 0; kt < 2; kt++)
#pragma unroll
        for (int nt = 0; nt < 4; nt++)
#pragma unroll
            for (int i = 0; i < 8; i++)
                bfr[kt][nt][i] = f2bs(W[(kt * 32 + lg * 8 + i) * 64 + nt * 16 + l15]);
    int ntiles = (n + 15) >> 4;
    for (int t = blockIdx.x * 4 + wid; t < ntiles; t += gridDim.x * 4) {
        int rowA = t * 16 + l15;
        if (rowA >= n) rowA = n - 1;
        const uint4* h = (const uint4*)(H + (size_t)rowA * 64);  // 8x uint4/row
        bf16x8 ap[2], an[2];
#pragma unroll
        for (int kt = 0; kt < 2; kt++) {
            uint4 hh = h[kt * 4 + lg];      // dims kt*32+lg*8 .. +7
            uint uu[4] = {hh.x, hh.y, hh.z, hh.w};
#pragma unroll
            for (int j = 0; j < 4; j++) {
                f32x2 lo = unpackfp8(uu[j]);     // dim 2j   (pos,neg)
                f32x2 hi = unpackfp8_hi(uu[j]);  // dim 2j+1
                ap[kt][2 * j]     = f2bs(lo.x); an[kt][2 * j]     = f2bs(lo.y);
                ap[kt][2 * j + 1] = f2bs(hi.x); an[kt][2 * j + 1] = f2bs(hi.y);
            }
        }
        f32x4 accp[4], accn[4];
#pragma unroll
        for (int nt = 0; nt < 4; nt++) { accp[nt] = (f32x4)0.f; accn[nt] = (f32x4)0.f; }
#pragma unroll
        for (int nt = 0; nt < 4; nt++) {
            accp[nt] = __builtin_amdgcn_mfma_f32_16x16x32_bf16(ap[0], bfr[0][nt], accp[nt], 0, 0, 0);
            accp[nt] = __builtin_amdgcn_mfma_f32_16x16x32_bf16(ap[1], bfr[1][nt], accp[nt], 0, 0, 0);
            accn[nt] = __builtin_amdgcn_mfma_f32_16x16x32_bf16(an[0], bfr[0][nt], accn[nt], 0, 0, 0);
            accn[nt] = __builtin_amdgcn_mfma_f32_16x16x32_bf16(an[1], bfr[1][nt], accn[nt], 0, 0, 0);
        }
        float dvr[4];
#pragma unroll
        for (int reg = 0; reg < 4; reg++) {
            int node = t * 16 + lg * 4 + reg;
            dvr[reg] = node < n ? rsqrtf((float)cnt[node] + 1.0f) : 0.f;
        }
#pragma unroll
        for (int nt = 0; nt < 4; nt++)
#pragma unroll
            for (int reg = 0; reg < 4; reg++) {
                int node = t * 16 + lg * 4 + reg;
                if (node < n)
                    out[(size_t)node * 64 + nt * 16 + l15] =
                        packfp8(accp[nt][reg] * dvr[reg], accn[nt][reg] * dvr[reg]);
            }
    }
}

// ---- fused GCN aggregation: fp8 gather in, fp8-packed out -----------------
// wave per node, lane = dim. Byte-offset addressing: one lshl_add per gather.
template <int MODE>
__global__ __launch_bounds__(256) void conv_packed(
        const ushort* __restrict__ g, const int* __restrict__ bucket,
        const int* __restrict__ off, const int* __restrict__ cnt,
        const float* __restrict__ bias,
        ushort* __restrict__ out, float* __restrict__ colpart, int n) {
    int lane = threadIdx.x & 63, wid = threadIdx.x >> 6;
    const uchar* gb = (const uchar*)g;
    uint l2 = (uint)lane * 2;
    __shared__ float s[256];
    float colp  = 0.f;
    float blane = bias[lane];
    int wstart = blockIdx.x * 4 + wid, wstride = gridDim.x * 4;
    for (int v = wstart; v < n; v += wstride) {
        int c = cnt[v];
        float dv = rsqrtf((float)c + 1.0f);
        f32x2 sv = unpackfp8(*(const ushort*)(gb + (((uint)v << 7) + l2)));
        float a0p = sv.x, a1p = 0.f, a2p = 0.f, a3p = 0.f;   // self in a0
        float a0n = sv.y, a1n = 0.f, a2n = 0.f, a3n = 0.f;
        const int*  bk  = bucket + off[v];
        const int4* bk4 = (const int4*)bk;
        int nq8 = c >> 3;
        for (int q = 0; q < nq8; q++) {
            int4 ra = bk4[2 * q], rb = bk4[2 * q + 1];
            uint u0 = *(const ushort*)(gb + (((uint)ra.x << 7) + l2));
            uint u1 = *(const ushort*)(gb + (((uint)ra.y << 7) + l2));
            uint u2 = *(const ushort*)(gb + (((uint)ra.z << 7) + l2));
            uint u3 = *(const ushort*)(gb + (((uint)ra.w << 7) + l2));
            uint u4 = *(const ushort*)(gb + (((uint)rb.x << 7) + l2));
            uint u5 = *(const ushort*)(gb + (((uint)rb.y << 7) + l2));
            uint u6 = *(const ushort*)(gb + (((uint)rb.z << 7) + l2));
            uint u7 = *(const ushort*)(gb + (((uint)rb.w << 7) + l2));
            f32x2 d0 = unpackfp8(u0), d1 = unpackfp8(u1);
            f32x2 d2 = unpackfp8(u2), d3 = unpackfp8(u3);
            f32x2 d4 = unpackfp8(u4), d5 = unpackfp8(u5);
            f32x2 d6 = unpackfp8(u6), d7 = unpackfp8(u7);
            a0p += d0.x + d4.x; a0n += d0.y + d4.y;
            a1p += d1.x + d5.x; a1n += d1.y + d5.y;
            a2p += d2.x + d6.x; a2n += d2.y + d6.y;
            a3p += d3.x + d7.x; a3n += d3.y + d7.y;
        }
        int i = nq8 << 3;
        if (c - i >= 4) {
            int4 r = bk4[i >> 2];
            f32x2 d0 = unpackfp8(*(const ushort*)(gb + (((uint)r.x << 7) + l2)));
            f32x2 d1 = unpackfp8(*(const ushort*)(gb + (((uint)r.y << 7) + l2)));
            f32x2 d2 = unpackfp8(*(const ushort*)(gb + (((uint)r.z << 7) + l2)));
            f32x2 d3 = unpackfp8(*(const ushort*)(gb + (((uint)r.w << 7) + l2)));
            a0p += d0.x; a0n += d0.y;
            a1p += d1.x; a1n += d1.y;
            a2p += d2.x; a2n += d2.y;
            a3p += d3.x; a3n += d3.y;
            i += 4;
        }
        for (; i < c; i++) {
            f32x2 d = unpackfp8(*(const ushort*)(gb + (((uint)bk[i] << 7) + l2)));
            a0p += d.x;
            a0n += d.y;
        }
        float sp = (a0p + a1p) + (a2p + a3p);
        float sn = (a0n + a1n) + (a2n + a3n);
        float rp = fmaf(dv, sp, blane);
        float rn = fmaf(dv, sn, blane);
        size_t vo = (size_t)v * 64 + lane;
        if (MODE == 0) {
            out[vo] = packfp8(fmaxf(rp, 0.f), fmaxf(rn, 0.f));
        } else {
            out[vo] = packfp8(rp, rn);
            colp += rp;          // f32 partial (pre-rounding) for summary
        }
    }
    if (MODE == 1) {
        s[wid * 64 + lane] = colp;
        __syncthreads();
        if (wid == 0) {
            float t = s[lane] + s[64 + lane] + s[128 + lane] + s[192 + lane];
            colpart[(size_t)blockIdx.x * 64 + lane] = t;
        }
    }
}

// ---- stage A: sum RB colpart rows per block -> colpart2 --------------------
__global__ __launch_bounds__(256) void colreduce_kernel(
        const float* __restrict__ colpart, float* __restrict__ colpart2) {
    int lane = threadIdx.x & 63, w = threadIdx.x >> 6;
    __shared__ float s4[4][64];
    float t = 0.f;
    int base = blockIdx.x * RB;
    for (int g = w; g < RB; g += 4) t += colpart[(size_t)(base + g) * 64 + lane];
    s4[w][lane] = t;
    __syncthreads();
    if (w == 0)
        colpart2[(size_t)blockIdx.x * 64 + lane] =
            s4[0][lane] + s4[1][lane] + s4[2][lane] + s4[3][lane];
}

// ---- summary + ws = W_dgi @ sigmoid(mean(pos_z)) ---------------------------
__global__ void summary_kernel(const float* __restrict__ colpart,
                               const float* __restrict__ Wdgi,
                               float* __restrict__ wsv, int G, float invN) {
    __shared__ float sm[64];
    __shared__ float s4[4][64];
    int lane = threadIdx.x & 63, w = threadIdx.x >> 6;
    float t = 0.f;
    for (int g = w; g < G; g += 4) t += colpart[(size_t)g * 64 + lane];
    s4[w][lane] = t;
    __syncthreads();
    if (w == 0) {
        t = s4[0][lane] + s4[1][lane] + s4[2][lane] + s4[3][lane];
        sm[lane] = 1.f / (1.f + expf(-t * invN));
    }
    __syncthreads();
    if (threadIdx.x < 64) {
        float a = 0.f;
        for (int j = 0; j < 64; j++) a += Wdgi[threadIdx.x * 64 + j] * sm[j];
        wsv[threadIdx.x] = a;
    }
}

// ---- both losses: 16-lane group per node, 4 nodes per wave-iteration -------
__global__ __launch_bounds__(256) void loss4_kernel(
        const ushort* __restrict__ z, const float* __restrict__ wsv,
        float* __restrict__ lossacc, int n) {
    int lane = threadIdx.x & 63, wid = threadIdx.x >> 6;
    int sub = lane >> 4, dch = lane & 15;
    __shared__ float s[16];
    float w0 = wsv[dch * 4], w1 = wsv[dch * 4 + 1];
    float w2 = wsv[dch * 4 + 2], w3 = wsv[dch * 4 + 3];
    float lp = 0.f, ln = 0.f;
    int nq = (n + 3) >> 2;
    for (int qi = blockIdx.x * 4 + wid; qi < nq; qi += gridDim.x * 4) {
        int v = qi * 4 + sub;
        float p = 0.f, q = 0.f;
        if (v < n) {
            uint2 u = *(const uint2*)(z + (size_t)v * 64 + dch * 4);   // 4 dims
            f32x2 a0 = unpackfp8(u.x), a1 = unpackfp8_hi(u.x);
            f32x2 a2 = unpackfp8(u.y), a3 = unpackfp8_hi(u.y);
            p = a0.x * w0 + a1.x * w1 + a2.x * w2 + a3.x * w3;
            q = a0.y * w0 + a1.y * w1 + a2.y * w2 + a3.y * w3;
        }
        for (int o = 1; o < 16; o <<= 1) {
            p += __shfl_xor(p, o, 64);
            q += __shfl_xor(q, o, 64);
        }
        if (dch == 0 && v < n) {
            lp += -logf(1.f / (1.f + expf(-p)) + 1e-15f);   // -log(sigmoid(p)+eps)
            ln += -logf(1.f / (1.f + expf( q)) + 1e-15f);   // -log(1-sigmoid(q)+eps)
        }
    }
    lp += __shfl_xor(lp, 16, 64); ln += __shfl_xor(ln, 16, 64);
    lp += __shfl_xor(lp, 32, 64); ln += __shfl_xor(ln, 32, 64);
    if (lane == 0) { s[wid] = lp; s[8 + wid] = ln; }
    __syncthreads();
    if (threadIdx.x == 0) atomicAdd(&lossacc[0], s[0] + s[1] + s[2] + s[3]);
    if (threadIdx.x == 1) atomicAdd(&lossacc[1], s[8] + s[9] + s[10] + s[11]);
}

__global__ void finalize_kernel(const float* __restrict__ lossacc,
                                float* __restrict__ out, float invN) {
    out[0] = (lossacc[0] + lossacc[1]) * invN;
}

// ---------------------------------------------------------------------------
extern "C" void kernel_launch(void* const* d_in, const int* in_sizes, int n_in,
                              void* d_out, int out_size, void* d_ws, size_t ws_size,
                              hipStream_t stream) {
    const float* x    = (const float*)d_in[0];
    const float* W1   = (const float*)d_in[1];
    const float* b1   = (const float*)d_in[2];
    const float* W2   = (const float*)d_in[3];
    const float* b2   = (const float*)d_in[4];
    const float* Wdgi = (const float*)d_in[5];
    const int*   edge = (const int*)d_in[6];
    const int*   perm = (const int*)d_in[7];

    const int N = in_sizes[7];
    const int E = in_sizes[6] / 2;
    const int* row = edge;
    const int* col = edge + E;
    const int nb = (N + NPB - 1) >> NB_SHIFT;

    char* wsb = (char*)d_ws;
    size_t woff = 0;
    auto alloc = [&](size_t bytes) -> void* {
        void* p = wsb + woff;
        woff = (woff + bytes + 255) & ~(size_t)255;
        return p;
    };
    int*    bucket   = (int*)  alloc((size_t)nb * BINREGION * 4);  // 9.6 MB
    uint*   bins     = (uint*) alloc((size_t)nb * BINCAP * 4);     // 8 MB
    int*    bincnt   = (int*)  alloc((size_t)nb * 4);
    int*    cnt      = (int*)  alloc((size_t)N * 4);
    int*    off      = (int*)  alloc((size_t)N * 4);
    ushort* G        = (ushort*)alloc((size_t)N * 64 * 2);         // fp8-packed, 12.8 MB
    ushort* H        = (ushort*)alloc((size_t)N * 64 * 2);         // fp8-packed, 12.8 MB
    float*  colpart  = (float*)alloc((size_t)GG * 64 * 4);
    float*  colpart2 = (float*)alloc((size_t)(GG / RB) * 64 * 4);
    float*  wsv      = (float*)alloc(64 * 4);
    float*  lossacc  = (float*)alloc(2 * 4);

    hipMemsetAsync(bincnt, 0, (size_t)nb * 4, stream);
    hipMemsetAsync(lossacc, 0, 8, stream);

    const int nchunks = (E + PCHUNK - 1) / PCHUNK;
    partition_edges<<<nchunks, 256, 0, stream>>>(row, col, bins, bincnt, E, nb);
    place_lds<<<nb, 256, 0, stream>>>(bins, bincnt, bucket, off, cnt, N);

    // layer 1: G = fp8((X @ W1) * dis) both branches, aggregate+relu -> H (fp8)
    gemm1_mfma<<<1024, 256, 0, stream>>>(x, W1, perm, cnt, G, N);
    conv_packed<0><<<GG, 256, 0, stream>>>(G, bucket, off, cnt, b1, H, nullptr, N);
    // layer 2: G = fp8((H @ W2) * dis), aggregate -> z (fp8, in H) + colpart
    gemm2_mfma<<<1024, 256, 0, stream>>>(H, W2, cnt, G, N);
    conv_packed<1><<<GG, 256, 0, stream>>>(G, bucket, off, cnt, b2, H, colpart, N);

    colreduce_kernel<<<GG / RB, 256, 0, stream>>>(colpart, colpart2);
    summary_kernel<<<1, 256, 0, stream>>>(colpart2, Wdgi, wsv, GG / RB, 1.0f / N);
    loss4_kernel<<<1024, 256, 0, stream>>>(H, wsv, lossacc, N);
    finalize_kernel<<<1, 1, 0, stream>>>(lossacc, (float*)d_out, 1.0f / N);
}

// Round 16
// 201.814 us; speedup vs baseline: 1.2053x; 1.0821x over previous
//
#include <hip/hip_runtime.h>
#include <hip/hip_bf16.h>
#include <math.h>

#define GG 2048          // conv grid (colpart rows)
#define RB 32            // colpart rows per stage-A block
#define NB_SHIFT 9       // 512 nodes per bin
#define NPB 512
#define BINCAP 10240     // edges per bin (mean 8192, 6-sigma ~8740)
#define BINREGION 12288  // padded words per bin bucket region (48 KB LDS window)
#define PCHUNK 2048      // edges per partition chunk (782 blocks for E=1.6M)

typedef __hip_bfloat16 bf16;
typedef unsigned int uint;
typedef unsigned short ushort;
typedef unsigned char uchar;
typedef short bf16x8 __attribute__((ext_vector_type(8)));
typedef float f32x4 __attribute__((ext_vector_type(4)));
typedef float f32x2 __attribute__((ext_vector_type(2)));

__device__ __forceinline__ bf16  f2b(float x) { return __float2bfloat16(x); }
__device__ __forceinline__ short f2bs(float x) {
    bf16 b = __float2bfloat16(x);
    return *reinterpret_cast<short*>(&b);
}
// fp8 e4m3-packed pos/neg (all intermediates): byte0=pos, byte1=neg per dim
__device__ __forceinline__ ushort packfp8(float p, float n) {
    return (ushort)__builtin_amdgcn_cvt_pk_fp8_f32(p, n, 0, false);
}
__device__ __forceinline__ f32x2 unpackfp8(uint u) {       // low 16 bits
    return __builtin_amdgcn_cvt_pk_f32_fp8((int)u, false);
}
__device__ __forceinline__ f32x2 unpackfp8_hi(uint u) {    // high 16 bits
    return __builtin_amdgcn_cvt_pk_f32_fp8((int)u, true);
}

// ---- P1: partition edges into bins of 512 nodes; packed u = (r<<9)|(c&511).
__global__ __launch_bounds__(256) void partition_edges(
        const int* __restrict__ row, const int* __restrict__ col,
        uint* __restrict__ bins, int* __restrict__ bincnt, int E, int nb) {
    __shared__ int lcnt[256];
    __shared__ int lbase[256];
    for (int chunk = blockIdx.x * PCHUNK; chunk < E; chunk += gridDim.x * PCHUNK) {
        int end = chunk + PCHUNK < E ? chunk + PCHUNK : E;
        if (threadIdx.x < nb) lcnt[threadIdx.x] = 0;
        __syncthreads();
        for (int e = chunk + threadIdx.x; e < end; e += 256)
            atomicAdd(&lcnt[col[e] >> NB_SHIFT], 1);
        __syncthreads();
        if (threadIdx.x < nb) {
            lbase[threadIdx.x] = atomicAdd(&bincnt[threadIdx.x], lcnt[threadIdx.x]);
            lcnt[threadIdx.x] = 0;
        }
        __syncthreads();
        for (int e = chunk + threadIdx.x; e < end; e += 256) {
            int c = col[e], r = row[e];
            int g = c >> NB_SHIFT;
            int dst = lbase[g] + atomicAdd(&lcnt[g], 1);
            if (dst < BINCAP)
                bins[(size_t)g * BINCAP + dst] = ((uint)r << NB_SHIFT) | (uint)(c & (NPB - 1));
        }
        __syncthreads();
    }
}

// ---- P2: one block per bin. LDS hist -> cnt; LDS padded prefix -> off;
// LDS-window scatter; coalesced int4 write-out. ------------------------------
__global__ __launch_bounds__(256) void place_lds(
        const uint* __restrict__ bins, const int* __restrict__ bincnt,
        int* __restrict__ bucket, int* __restrict__ off, int* __restrict__ cnt,
        int N) {
    __shared__ int lcnt[NPB];
    __shared__ int s[NPB];
    __shared__ int win[BINREGION];
    int b  = blockIdx.x;
    int lo = b << NB_SHIFT;
    int base = b * BINREGION;
    int ne = bincnt[b];
    if (ne > BINCAP) ne = BINCAP;
    const uint* be = bins + (size_t)b * BINCAP;
    for (int i = threadIdx.x; i < NPB; i += 256) lcnt[i] = 0;
    __syncthreads();
    for (int i = threadIdx.x; i < ne; i += 256)
        atomicAdd(&lcnt[be[i] & (NPB - 1)], 1);
    __syncthreads();
    int i0 = threadIdx.x, i1 = threadIdx.x + 256;
    s[i0] = (lcnt[i0] + 3) & ~3;
    s[i1] = (lcnt[i1] + 3) & ~3;
    __syncthreads();
    for (int st = 1; st < NPB; st <<= 1) {
        int v0 = i0 >= st ? s[i0 - st] : 0;
        int v1 = i1 >= st ? s[i1 - st] : 0;
        __syncthreads();
        s[i0] += v0; s[i1] += v1;
        __syncthreads();
    }
    for (int i = threadIdx.x; i < NPB; i += 256) {
        int v = lo + i;
        int pc = (lcnt[i] + 3) & ~3;
        int start = s[i] - pc;
        if (v < N) { off[v] = base + start; cnt[v] = lcnt[i]; }
        lcnt[i] = start;
    }
    __syncthreads();
    for (int i = threadIdx.x; i < ne; i += 256) {
        uint u = be[i];
        int slot = atomicAdd(&lcnt[u & (NPB - 1)], 1);
        if (slot < BINREGION) win[slot] = (int)(u >> NB_SHIFT);
    }
    __syncthreads();
    int wsize = s[NPB - 1];
    if (wsize > BINREGION) wsize = BINREGION;
    for (int i = threadIdx.x * 4; i < wsize; i += 1024)
        *(int4*)&bucket[base + i] = *(const int4*)&win[i];
}

// ---- layer-1 GEMM via MFMA; fp8-packed output -----------------------------
__global__ __launch_bounds__(256) void gemm1_mfma(
        const float* __restrict__ X, const float* __restrict__ W,
        const int* __restrict__ perm, const int* __restrict__ cnt,
        ushort* __restrict__ out, int n) {
    int lane = threadIdx.x & 63, wid = threadIdx.x >> 6;
    int l15 = lane & 15, lg = lane >> 4;
    bf16x8 bfr[2][4];
#pragma unroll
    for (int kt = 0; kt < 2; kt++)
#pragma unroll
        for (int nt = 0; nt < 4; nt++)
#pragma unroll
            for (int i = 0; i < 8; i++)
                bfr[kt][nt][i] = f2bs(W[(kt * 32 + lg * 8 + i) * 64 + nt * 16 + l15]);
    int ntiles = (n + 15) >> 4;
    for (int t = blockIdx.x * 4 + wid; t < ntiles; t += gridDim.x * 4) {
        int rowA = t * 16 + l15;
        if (rowA >= n) rowA = n - 1;
        int prow = perm[rowA];
        const float4* xp = (const float4*)(X + (size_t)rowA * 64);
        const float4* xn = (const float4*)(X + (size_t)prow * 64);
        bf16x8 ap[2], an[2];
#pragma unroll
        for (int kt = 0; kt < 2; kt++) {
            float4 p0 = xp[kt * 8 + lg * 2], p1 = xp[kt * 8 + lg * 2 + 1];
            float4 n0 = xn[kt * 8 + lg * 2], n1 = xn[kt * 8 + lg * 2 + 1];
            ap[kt][0] = f2bs(p0.x); ap[kt][1] = f2bs(p0.y);
            ap[kt][2] = f2bs(p0.z); ap[kt][3] = f2bs(p0.w);
            ap[kt][4] = f2bs(p1.x); ap[kt][5] = f2bs(p1.y);
            ap[kt][6] = f2bs(p1.z); ap[kt][7] = f2bs(p1.w);
            an[kt][0] = f2bs(n0.x); an[kt][1] = f2bs(n0.y);
            an[kt][2] = f2bs(n0.z); an[kt][3] = f2bs(n0.w);
            an[kt][4] = f2bs(n1.x); an[kt][5] = f2bs(n1.y);
            an[kt][6] = f2bs(n1.z); an[kt][7] = f2bs(n1.w);
        }
        f32x4 accp[4], accn[4];
#pragma unroll
        for (int nt = 0; nt < 4; nt++) { accp[nt] = (f32x4)0.f; accn[nt] = (f32x4)0.f; }
#pragma unroll
        for (int nt = 0; nt < 4; nt++) {
            accp[nt] = __builtin_amdgcn_mfma_f32_16x16x32_bf16(ap[0], bfr[0][nt], accp[nt], 0, 0, 0);
            accp[nt] = __builtin_amdgcn_mfma_f32_16x16x32_bf16(ap[1], bfr[1][nt], accp[nt], 0, 0, 0);
            accn[nt] = __builtin_amdgcn_mfma_f32_16x16x32_bf16(an[0], bfr[0][nt], accn[nt], 0, 0, 0);
            accn[nt] = __builtin_amdgcn_mfma_f32_16x16x32_bf16(an[1], bfr[1][nt], accn[nt], 0, 0, 0);
        }
        float dvr[4];
#pragma unroll
        for (int reg = 0; reg < 4; reg++) {
            int node = t * 16 + lg * 4 + reg;
            dvr[reg] = node < n ? rsqrtf((float)cnt[node] + 1.0f) : 0.f;
        }
#pragma unroll
        for (int nt = 0; nt < 4; nt++)
#pragma unroll
            for (int reg = 0; reg < 4; reg++) {
                int node = t * 16 + lg * 4 + reg;
                if (node < n)
                    out[(size_t)node * 64 + nt * 16 + l15] =
                        packfp8(accp[nt][reg] * dvr[reg], accn[nt][reg] * dvr[reg]);
            }
    }
}

// ---- layer-2 GEMM via MFMA, fp8-packed in (unpack->bf16), fp8 out ---------
__global__ __launch_bounds__(256) void gemm2_mfma(
        const ushort* __restrict__ H, const float* __restrict__ W,
        const int* __restrict__ cnt, ushort* __restrict__ out, int n) {
    int lane = threadIdx.x & 63, wid = threadIdx.x >> 6;
    int l15 = lane & 15, lg = lane >> 4;
    bf16x8 bfr[2][4];
#pragma unroll
    for (int kt = 0; kt < 2; kt++)
#pragma unroll
        for (int nt = 0; nt < 4; nt++)
#pragma unroll
            for (int i = 0; i < 8; i++)
                bfr[kt][nt][i] = f2bs(W[(kt * 32 + lg * 8 + i) * 64 + nt * 16 + l15]);
    int ntiles = (n + 15) >> 4;
    for (int t = blockIdx.x * 4 + wid; t < ntiles; t += gridDim.x * 4) {
        int rowA = t * 16 + l15;
        if (rowA >= n) rowA = n - 1;
        const uint4* h = (const uint4*)(H + (size_t)rowA * 64);  // 8x uint4/row
        bf16x8 ap[2], an[2];
#pragma unroll
        for (int kt = 0; kt < 2; kt++) {
            uint4 hh = h[kt * 4 + lg];      // dims kt*32+lg*8 .. +7
            uint uu[4] = {hh.x, hh.y, hh.z, hh.w};
#pragma unroll
            for (int j = 0; j < 4; j++) {
                f32x2 lo = unpackfp8(uu[j]);     // dim 2j   (pos,neg)
                f32x2 hi = unpackfp8_hi(uu[j]);  // dim 2j+1
                ap[kt][2 * j]     = f2bs(lo.x); an[kt][2 * j]     = f2bs(lo.y);
                ap[kt][2 * j + 1] = f2bs(hi.x); an[kt][2 * j + 1] = f2bs(hi.y);
            }
        }
        f32x4 accp[4], accn[4];
#pragma unroll
        for (int nt = 0; nt < 4; nt++) { accp[nt] = (f32x4)0.f; accn[nt] = (f32x4)0.f; }
#pragma unroll
        for (int nt = 0; nt < 4; nt++) {
            accp[nt] = __builtin_amdgcn_mfma_f32_16x16x32_bf16(ap[0], bfr[0][nt], accp[nt], 0, 0, 0);
            accp[nt] = __builtin_amdgcn_mfma_f32_16x16x32_bf16(ap[1], bfr[1][nt], accp[nt], 0, 0, 0);
            accn[nt] = __builtin_amdgcn_mfma_f32_16x16x32_bf16(an[0], bfr[0][nt], accn[nt], 0, 0, 0);
            accn[nt] = __builtin_amdgcn_mfma_f32_16x16x32_bf16(an[1], bfr[1][nt], accn[nt], 0, 0, 0);
        }
        float dvr[4];
#pragma unroll
        for (int reg = 0; reg < 4; reg++) {
            int node = t * 16 + lg * 4 + reg;
            dvr[reg] = node < n ? rsqrtf((float)cnt[node] + 1.0f) : 0.f;
        }
#pragma unroll
        for (int nt = 0; nt < 4; nt++)
#pragma unroll
            for (int reg = 0; reg < 4; reg++) {
                int node = t * 16 + lg * 4 + reg;
                if (node < n)
                    out[(size_t)node * 64 + nt * 16 + l15] =
                        packfp8(accp[nt][reg] * dvr[reg], accn[nt][reg] * dvr[reg]);
            }
    }
}

// ---- fused GCN aggregation: scalar-pipe addressing + packed f32x2 adds ----
// wave per node. v is wave-uniform -> readfirstlane makes cnt/off/bucket
// loads s_loads; gather = SGPR row base + VGPR lane offset; accumulate with
// v_pk_add_f32 on (pos,neg) pairs.
template <int MODE>
__global__ __launch_bounds__(256) void conv_packed(
        const ushort* __restrict__ g, const int* __restrict__ bucket,
        const int* __restrict__ off, const int* __restrict__ cnt,
        const float* __restrict__ bias,
        ushort* __restrict__ out, float* __restrict__ colpart, int n) {
    int lane = threadIdx.x & 63, wid = threadIdx.x >> 6;
    const uchar* gb = (const uchar*)g;
    uint l2 = (uint)lane * 2;
    __shared__ float s[256];
    float colp  = 0.f;
    float blane = bias[lane];
    int wstart = blockIdx.x * 4 + wid, wstride = gridDim.x * 4;
    for (int v = wstart; v < n; v += wstride) {
        int vu  = __builtin_amdgcn_readfirstlane(v);
        int c   = cnt[vu];              // s_load
        int ofs = off[vu];              // s_load
        float dv = rsqrtf((float)c + 1.0f);
        f32x2 acc0 = unpackfp8(*(const ushort*)(gb + ((size_t)(uint)vu << 7) + l2));
        f32x2 acc1 = {0.f, 0.f}, acc2 = {0.f, 0.f}, acc3 = {0.f, 0.f};
        f32x2 acc4 = {0.f, 0.f}, acc5 = {0.f, 0.f}, acc6 = {0.f, 0.f}, acc7 = {0.f, 0.f};
        const int*  bk  = bucket + ofs;            // uniform base
        const int4* bk4 = (const int4*)bk;
        int nq16 = c >> 4;
        for (int q = 0; q < nq16; q++) {           // 16 gathers in flight
            int4 ra = bk4[4 * q],     rb = bk4[4 * q + 1];
            int4 rc = bk4[4 * q + 2], rd = bk4[4 * q + 3];
            uint u0  = *(const ushort*)(gb + ((size_t)(uint)ra.x << 7) + l2);
            uint u1  = *(const ushort*)(gb + ((size_t)(uint)ra.y << 7) + l2);
            uint u2  = *(const ushort*)(gb + ((size_t)(uint)ra.z << 7) + l2);
            uint u3  = *(const ushort*)(gb + ((size_t)(uint)ra.w << 7) + l2);
            uint u4  = *(const ushort*)(gb + ((size_t)(uint)rb.x << 7) + l2);
            uint u5  = *(const ushort*)(gb + ((size_t)(uint)rb.y << 7) + l2);
            uint u6  = *(const ushort*)(gb + ((size_t)(uint)rb.z << 7) + l2);
            uint u7  = *(const ushort*)(gb + ((size_t)(uint)rb.w << 7) + l2);
            uint u8  = *(const ushort*)(gb + ((size_t)(uint)rc.x << 7) + l2);
            uint u9  = *(const ushort*)(gb + ((size_t)(uint)rc.y << 7) + l2);
            uint u10 = *(const ushort*)(gb + ((size_t)(uint)rc.z << 7) + l2);
            uint u11 = *(const ushort*)(gb + ((size_t)(uint)rc.w << 7) + l2);
            uint u12 = *(const ushort*)(gb + ((size_t)(uint)rd.x << 7) + l2);
            uint u13 = *(const ushort*)(gb + ((size_t)(uint)rd.y << 7) + l2);
            uint u14 = *(const ushort*)(gb + ((size_t)(uint)rd.z << 7) + l2);
            uint u15 = *(const ushort*)(gb + ((size_t)(uint)rd.w << 7) + l2);
            acc0 += unpackfp8(u0);  acc1 += unpackfp8(u1);
            acc2 += unpackfp8(u2);  acc3 += unpackfp8(u3);
            acc4 += unpackfp8(u4);  acc5 += unpackfp8(u5);
            acc6 += unpackfp8(u6);  acc7 += unpackfp8(u7);
            acc0 += unpackfp8(u8);  acc1 += unpackfp8(u9);
            acc2 += unpackfp8(u10); acc3 += unpackfp8(u11);
            acc4 += unpackfp8(u12); acc5 += unpackfp8(u13);
            acc6 += unpackfp8(u14); acc7 += unpackfp8(u15);
        }
        int i = nq16 << 4;
        for (; i + 4 <= c; i += 4) {
            int4 r = *(const int4*)(bk + i);
            acc0 += unpackfp8(*(const ushort*)(gb + ((size_t)(uint)r.x << 7) + l2));
            acc1 += unpackfp8(*(const ushort*)(gb + ((size_t)(uint)r.y << 7) + l2));
            acc2 += unpackfp8(*(const ushort*)(gb + ((size_t)(uint)r.z << 7) + l2));
            acc3 += unpackfp8(*(const ushort*)(gb + ((size_t)(uint)r.w << 7) + l2));
        }
        for (; i < c; i++) {
            int r = bk[i];
            acc0 += unpackfp8(*(const ushort*)(gb + ((size_t)(uint)r << 7) + l2));
        }
        f32x2 acc = ((acc0 + acc1) + (acc2 + acc3)) + ((acc4 + acc5) + (acc6 + acc7));
        float rp = fmaf(dv, acc.x, blane);
        float rn = fmaf(dv, acc.y, blane);
        size_t vo = (size_t)vu * 64 + lane;
        if (MODE == 0) {
            out[vo] = packfp8(fmaxf(rp, 0.f), fmaxf(rn, 0.f));
        } else {
            out[vo] = packfp8(rp, rn);
            colp += rp;          // f32 partial (pre-rounding) for summary
        }
    }
    if (MODE == 1) {
        s[wid * 64 + lane] = colp;
        __syncthreads();
        if (wid == 0) {
            float t = s[lane] + s[64 + lane] + s[128 + lane] + s[192 + lane];
            colpart[(size_t)blockIdx.x * 64 + lane] = t;
        }
    }
}

// ---- stage A: sum RB colpart rows per block -> colpart2 --------------------
__global__ __launch_bounds__(256) void colreduce_kernel(
        const float* __restrict__ colpart, float* __restrict__ colpart2) {
    int lane = threadIdx.x & 63, w = threadIdx.x >> 6;
    __shared__ float s4[4][64];
    float t = 0.f;
    int base = blockIdx.x * RB;
    for (int g = w; g < RB; g += 4) t += colpart[(size_t)(base + g) * 64 + lane];
    s4[w][lane] = t;
    __syncthreads();
    if (w == 0)
        colpart2[(size_t)blockIdx.x * 64 + lane] =
            s4[0][lane] + s4[1][lane] + s4[2][lane] + s4[3][lane];
}

// ---- summary + ws = W_dgi @ sigmoid(mean(pos_z)) ---------------------------
__global__ void summary_kernel(const float* __restrict__ colpart,
                               const float* __restrict__ Wdgi,
                               float* __restrict__ wsv, int G, float invN) {
    __shared__ float sm[64];
    __shared__ float s4[4][64];
    int lane = threadIdx.x & 63, w = threadIdx.x >> 6;
    float t = 0.f;
    for (int g = w; g < G; g += 4) t += colpart[(size_t)g * 64 + lane];
    s4[w][lane] = t;
    __syncthreads();
    if (w == 0) {
        t = s4[0][lane] + s4[1][lane] + s4[2][lane] + s4[3][lane];
        sm[lane] = 1.f / (1.f + expf(-t * invN));
    }
    __syncthreads();
    if (threadIdx.x < 64) {
        float a = 0.f;
        for (int j = 0; j < 64; j++) a += Wdgi[threadIdx.x * 64 + j] * sm[j];
        wsv[threadIdx.x] = a;
    }
}

// ---- both losses: 16-lane group per node, 4 nodes per wave-iteration -------
__global__ __launch_bounds__(256) void loss4_kernel(
        const ushort* __restrict__ z, const float* __restrict__ wsv,
        float* __restrict__ lossacc, int n) {
    int lane = threadIdx.x & 63, wid = threadIdx.x >> 6;
    int sub = lane >> 4, dch = lane & 15;
    __shared__ float s[16];
    float w0 = wsv[dch * 4], w1 = wsv[dch * 4 + 1];
    float w2 = wsv[dch * 4 + 2], w3 = wsv[dch * 4 + 3];
    float lp = 0.f, ln = 0.f;
    int nq = (n + 3) >> 2;
    for (int qi = blockIdx.x * 4 + wid; qi < nq; qi += gridDim.x * 4) {
        int v = qi * 4 + sub;
        float p = 0.f, q = 0.f;
        if (v < n) {
            uint2 u = *(const uint2*)(z + (size_t)v * 64 + dch * 4);   // 4 dims
            f32x2 a0 = unpackfp8(u.x), a1 = unpackfp8_hi(u.x);
            f32x2 a2 = unpackfp8(u.y), a3 = unpackfp8_hi(u.y);
            p = a0.x * w0 + a1.x * w1 + a2.x * w2 + a3.x * w3;
            q = a0.y * w0 + a1.y * w1 + a2.y * w2 + a3.y * w3;
        }
        for (int o = 1; o < 16; o <<= 1) {
            p += __shfl_xor(p, o, 64);
            q += __shfl_xor(q, o, 64);
        }
        if (dch == 0 && v < n) {
            lp += -logf(1.f / (1.f + expf(-p)) + 1e-15f);   // -log(sigmoid(p)+eps)
            ln += -logf(1.f / (1.f + expf( q)) + 1e-15f);   // -log(1-sigmoid(q)+eps)
        }
    }
    lp += __shfl_xor(lp, 16, 64); ln += __shfl_xor(ln, 16, 64);
    lp += __shfl_xor(lp, 32, 64); ln += __shfl_xor(ln, 32, 64);
    if (lane == 0) { s[wid] = lp; s[8 + wid] = ln; }
    __syncthreads();
    if (threadIdx.x == 0) atomicAdd(&lossacc[0], s[0] + s[1] + s[2] + s[3]);
    if (threadIdx.x == 1) atomicAdd(&lossacc[1], s[8] + s[9] + s[10] + s[11]);
}

__global__ void finalize_kernel(const float* __restrict__ lossacc,
                                float* __restrict__ out, float invN) {
    out[0] = (lossacc[0] + lossacc[1]) * invN;
}

// ---------------------------------------------------------------------------
extern "C" void kernel_launch(void* const* d_in, const int* in_sizes, int n_in,
                              void* d_out, int out_size, void* d_ws, size_t ws_size,
                              hipStream_t stream) {
    const float* x    = (const float*)d_in[0];
    const float* W1   = (const float*)d_in[1];
    const float* b1   = (const float*)d_in[2];
    const float* W2   = (const float*)d_in[3];
    const float* b2   = (const float*)d_in[4];
    const float* Wdgi = (const float*)d_in[5];
    const int*   edge = (const int*)d_in[6];
    const int*   perm = (const int*)d_in[7];

    const int N = in_sizes[7];
    const int E = in_sizes[6] / 2;
    const int* row = edge;
    const int* col = edge + E;
    const int nb = (N + NPB - 1) >> NB_SHIFT;

    char* wsb = (char*)d_ws;
    size_t woff = 0;
    auto alloc = [&](size_t bytes) -> void* {
        void* p = wsb + woff;
        woff = (woff + bytes + 255) & ~(size_t)255;
        return p;
    };
    int*    bucket   = (int*)  alloc((size_t)nb * BINREGION * 4);  // 9.6 MB
    uint*   bins     = (uint*) alloc((size_t)nb * BINCAP * 4);     // 8 MB
    int*    bincnt   = (int*)  alloc((size_t)nb * 4);
    int*    cnt      = (int*)  alloc((size_t)N * 4);
    int*    off      = (int*)  alloc((size_t)N * 4);
    ushort* G        = (ushort*)alloc((size_t)N * 64 * 2);         // fp8-packed, 12.8 MB
    ushort* H        = (ushort*)alloc((size_t)N * 64 * 2);         // fp8-packed, 12.8 MB
    float*  colpart  = (float*)alloc((size_t)GG * 64 * 4);
    float*  colpart2 = (float*)alloc((size_t)(GG / RB) * 64 * 4);
    float*  wsv      = (float*)alloc(64 * 4);
    float*  lossacc  = (float*)alloc(2 * 4);

    hipMemsetAsync(bincnt, 0, (size_t)nb * 4, stream);
    hipMemsetAsync(lossacc, 0, 8, stream);

    const int nchunks = (E + PCHUNK - 1) / PCHUNK;
    partition_edges<<<nchunks, 256, 0, stream>>>(row, col, bins, bincnt, E, nb);
    place_lds<<<nb, 256, 0, stream>>>(bins, bincnt, bucket, off, cnt, N);

    // layer 1: G = fp8((X @ W1) * dis) both branches, aggregate+relu -> H (fp8)
    gemm1_mfma<<<1024, 256, 0, stream>>>(x, W1, perm, cnt, G, N);
    conv_packed<0><<<GG, 256, 0, stream>>>(G, bucket, off, cnt, b1, H, nullptr, N);
    // layer 2: G = fp8((H @ W2) * dis), aggregate -> z (fp8, in H) + colpart
    gemm2_mfma<<<1024, 256, 0, stream>>>(H, W2, cnt, G, N);
    conv_packed<1><<<GG, 256, 0, stream>>>(G, bucket, off, cnt, b2, H, colpart, N);

    colreduce_kernel<<<GG / RB, 256, 0, stream>>>(colpart, colpart2);
    summary_kernel<<<1, 256, 0, stream>>>(colpart2, Wdgi, wsv, GG / RB, 1.0f / N);
    loss4_kernel<<<1024, 256, 0, stream>>>(H, wsv, lossacc, N);
    finalize_kernel<<<1, 1, 0, stream>>>(lossacc, (float*)d_out, 1.0f / N);
}

// Round 17
// 198.715 us; speedup vs baseline: 1.2241x; 1.0156x over previous
//
#include <hip/hip_runtime.h>
#include <hip/hip_bf16.h>
#include <math.h>

#define GG 2048          // conv grid (colpart rows)
#define RB 32            // colpart rows per stage-A block
#define NB_SHIFT 9       // 512 nodes per bin
#define NPB 512
#define BINCAP 10240     // edges per bin (mean 8192, 6-sigma ~8740)
#define BINREGION 12288  // padded words per bin bucket region (48 KB LDS window)
#define PCHUNK 2048      // edges per partition chunk (782 blocks for E=1.6M)

typedef __hip_bfloat16 bf16;
typedef unsigned int uint;
typedef unsigned short ushort;
typedef unsigned char uchar;
typedef short bf16x8 __attribute__((ext_vector_type(8)));
typedef float f32x4 __attribute__((ext_vector_type(4)));
typedef float f32x2 __attribute__((ext_vector_type(2)));

__device__ __forceinline__ bf16  f2b(float x) { return __float2bfloat16(x); }
__device__ __forceinline__ short f2bs(float x) {
    bf16 b = __float2bfloat16(x);
    return *reinterpret_cast<short*>(&b);
}
// fp8 e4m3-packed pos/neg (all intermediates): byte0=pos, byte1=neg per dim
__device__ __forceinline__ ushort packfp8(float p, float n) {
    return (ushort)__builtin_amdgcn_cvt_pk_fp8_f32(p, n, 0, false);
}
__device__ __forceinline__ f32x2 unpackfp8(uint u) {       // low 16 bits
    return __builtin_amdgcn_cvt_pk_f32_fp8((int)u, false);
}
__device__ __forceinline__ f32x2 unpackfp8_hi(uint u) {    // high 16 bits
    return __builtin_amdgcn_cvt_pk_f32_fp8((int)u, true);
}

// ---- zero bincnt + lossacc (replaces hipMemsetAsync graph nodes: each
// memset node measured ~42 us in graph replay; this kernel is ~2 us) --------
__global__ void zero_kernel(int* __restrict__ bincnt, float* __restrict__ lossacc,
                            int nb) {
    int i = threadIdx.x;
    if (i < nb) bincnt[i] = 0;
    if (i < 2)  lossacc[i] = 0.f;
}

// ---- P1: partition edges into bins of 512 nodes; packed u = (r<<9)|(c&511).
__global__ __launch_bounds__(256) void partition_edges(
        const int* __restrict__ row, const int* __restrict__ col,
        uint* __restrict__ bins, int* __restrict__ bincnt, int E, int nb) {
    __shared__ int lcnt[256];
    __shared__ int lbase[256];
    for (int chunk = blockIdx.x * PCHUNK; chunk < E; chunk += gridDim.x * PCHUNK) {
        int end = chunk + PCHUNK < E ? chunk + PCHUNK : E;
        if (threadIdx.x < nb) lcnt[threadIdx.x] = 0;
        __syncthreads();
        for (int e = chunk + threadIdx.x; e < end; e += 256)
            atomicAdd(&lcnt[col[e] >> NB_SHIFT], 1);
        __syncthreads();
        if (threadIdx.x < nb) {
            lbase[threadIdx.x] = atomicAdd(&bincnt[threadIdx.x], lcnt[threadIdx.x]);
            lcnt[threadIdx.x] = 0;
        }
        __syncthreads();
        for (int e = chunk + threadIdx.x; e < end; e += 256) {
            int c = col[e], r = row[e];
            int g = c >> NB_SHIFT;
            int dst = lbase[g] + atomicAdd(&lcnt[g], 1);
            if (dst < BINCAP)
                bins[(size_t)g * BINCAP + dst] = ((uint)r << NB_SHIFT) | (uint)(c & (NPB - 1));
        }
        __syncthreads();
    }
}

// ---- P2: one block per bin. LDS hist -> cnt; LDS padded prefix -> off;
// LDS-window scatter; coalesced int4 write-out. ------------------------------
__global__ __launch_bounds__(256) void place_lds(
        const uint* __restrict__ bins, const int* __restrict__ bincnt,
        int* __restrict__ bucket, int* __restrict__ off, int* __restrict__ cnt,
        int N) {
    __shared__ int lcnt[NPB];
    __shared__ int s[NPB];
    __shared__ int win[BINREGION];
    int b  = blockIdx.x;
    int lo = b << NB_SHIFT;
    int base = b * BINREGION;
    int ne = bincnt[b];
    if (ne > BINCAP) ne = BINCAP;
    const uint* be = bins + (size_t)b * BINCAP;
    for (int i = threadIdx.x; i < NPB; i += 256) lcnt[i] = 0;
    __syncthreads();
    for (int i = threadIdx.x; i < ne; i += 256)
        atomicAdd(&lcnt[be[i] & (NPB - 1)], 1);
    __syncthreads();
    int i0 = threadIdx.x, i1 = threadIdx.x + 256;
    s[i0] = (lcnt[i0] + 3) & ~3;
    s[i1] = (lcnt[i1] + 3) & ~3;
    __syncthreads();
    for (int st = 1; st < NPB; st <<= 1) {
        int v0 = i0 >= st ? s[i0 - st] : 0;
        int v1 = i1 >= st ? s[i1 - st] : 0;
        __syncthreads();
        s[i0] += v0; s[i1] += v1;
        __syncthreads();
    }
    for (int i = threadIdx.x; i < NPB; i += 256) {
        int v = lo + i;
        int pc = (lcnt[i] + 3) & ~3;
        int start = s[i] - pc;
        if (v < N) { off[v] = base + start; cnt[v] = lcnt[i]; }
        lcnt[i] = start;
    }
    __syncthreads();
    for (int i = threadIdx.x; i < ne; i += 256) {
        uint u = be[i];
        int slot = atomicAdd(&lcnt[u & (NPB - 1)], 1);
        if (slot < BINREGION) win[slot] = (int)(u >> NB_SHIFT);
    }
    __syncthreads();
    int wsize = s[NPB - 1];
    if (wsize > BINREGION) wsize = BINREGION;
    for (int i = threadIdx.x * 4; i < wsize; i += 1024)
        *(int4*)&bucket[base + i] = *(const int4*)&win[i];
}

// ---- layer-1 GEMM via MFMA; fp8-packed output -----------------------------
__global__ __launch_bounds__(256) void gemm1_mfma(
        const float* __restrict__ X, const float* __restrict__ W,
        const int* __restrict__ perm, const int* __restrict__ cnt,
        ushort* __restrict__ out, int n) {
    int lane = threadIdx.x & 63, wid = threadIdx.x >> 6;
    int l15 = lane & 15, lg = lane >> 4;
    bf16x8 bfr[2][4];
#pragma unroll
    for (int kt = 0; kt < 2; kt++)
#pragma unroll
        for (int nt = 0; nt < 4; nt++)
#pragma unroll
            for (int i = 0; i < 8; i++)
                bfr[kt][nt][i] = f2bs(W[(kt * 32 + lg * 8 + i) * 64 + nt * 16 + l15]);
    int ntiles = (n + 15) >> 4;
    for (int t = blockIdx.x * 4 + wid; t < ntiles; t += gridDim.x * 4) {
        int rowA = t * 16 + l15;
        if (rowA >= n) rowA = n - 1;
        int prow = perm[rowA];
        const float4* xp = (const float4*)(X + (size_t)rowA * 64);
        const float4* xn = (const float4*)(X + (size_t)prow * 64);
        bf16x8 ap[2], an[2];
#pragma unroll
        for (int kt = 0; kt < 2; kt++) {
            float4 p0 = xp[kt * 8 + lg * 2], p1 = xp[kt * 8 + lg * 2 + 1];
            float4 n0 = xn[kt * 8 + lg * 2], n1 = xn[kt * 8 + lg * 2 + 1];
            ap[kt][0] = f2bs(p0.x); ap[kt][1] = f2bs(p0.y);
            ap[kt][2] = f2bs(p0.z); ap[kt][3] = f2bs(p0.w);
            ap[kt][4] = f2bs(p1.x); ap[kt][5] = f2bs(p1.y);
            ap[kt][6] = f2bs(p1.z); ap[kt][7] = f2bs(p1.w);
            an[kt][0] = f2bs(n0.x); an[kt][1] = f2bs(n0.y);
            an[kt][2] = f2bs(n0.z); an[kt][3] = f2bs(n0.w);
            an[kt][4] = f2bs(n1.x); an[kt][5] = f2bs(n1.y);
            an[kt][6] = f2bs(n1.z); an[kt][7] = f2bs(n1.w);
        }
        f32x4 accp[4], accn[4];
#pragma unroll
        for (int nt = 0; nt < 4; nt++) { accp[nt] = (f32x4)0.f; accn[nt] = (f32x4)0.f; }
#pragma unroll
        for (int nt = 0; nt < 4; nt++) {
            accp[nt] = __builtin_amdgcn_mfma_f32_16x16x32_bf16(ap[0], bfr[0][nt], accp[nt], 0, 0, 0);
            accp[nt] = __builtin_amdgcn_mfma_f32_16x16x32_bf16(ap[1], bfr[1][nt], accp[nt], 0, 0, 0);
            accn[nt] = __builtin_amdgcn_mfma_f32_16x16x32_bf16(an[0], bfr[0][nt], accn[nt], 0, 0, 0);
            accn[nt] = __builtin_amdgcn_mfma_f32_16x16x32_bf16(an[1], bfr[1][nt], accn[nt], 0, 0, 0);
        }
        float dvr[4];
#pragma unroll
        for (int reg = 0; reg < 4; reg++) {
            int node = t * 16 + lg * 4 + reg;
            dvr[reg] = node < n ? rsqrtf((float)cnt[node] + 1.0f) : 0.f;
        }
#pragma unroll
        for (int nt = 0; nt < 4; nt++)
#pragma unroll
            for (int reg = 0; reg < 4; reg++) {
                int node = t * 16 + lg * 4 + reg;
                if (node < n)
                    out[(size_t)node * 64 + nt * 16 + l15] =
                        packfp8(accp[nt][reg] * dvr[reg], accn[nt][reg] * dvr[reg]);
            }
    }
}

// ---- layer-2 GEMM via MFMA, fp8-packed in (unpack->bf16), fp8 out ---------
__global__ __launch_bounds__(256) void gemm2_mfma(
        const ushort* __restrict__ H, const float* __restrict__ W,
        const int* __restrict__ cnt, ushort* __restrict__ out, int n) {
    int lane = threadIdx.x & 63, wid = threadIdx.x >> 6;
    int l15 = lane & 15, lg = lane >> 4;
    bf16x8 bfr[2][4];
#pragma unroll
    for (int kt = 0; kt < 2; kt++)
#pragma unroll
        for (int nt = 0; nt < 4; nt++)
#pragma unroll
            for (int i = 0; i < 8; i++)
                bfr[kt][nt][i] = f2bs(W[(kt * 32 + lg * 8 + i) * 64 + nt * 16 + l15]);
    int ntiles = (n + 15) >> 4;
    for (int t = blockIdx.x * 4 + wid; t < ntiles; t += gridDim.x * 4) {
        int rowA = t * 16 + l15;
        if (rowA >= n) rowA = n - 1;
        const uint4* h = (const uint4*)(H + (size_t)rowA * 64);  // 8x uint4/row
        bf16x8 ap[2], an[2];
#pragma unroll
        for (int kt = 0; kt < 2; kt++) {
            uint4 hh = h[kt * 4 + lg];      // dims kt*32+lg*8 .. +7
            uint uu[4] = {hh.x, hh.y, hh.z, hh.w};
#pragma unroll
            for (int j = 0; j < 4; j++) {
                f32x2 lo = unpackfp8(uu[j]);     // dim 2j   (pos,neg)
                f32x2 hi = unpackfp8_hi(uu[j]);  // dim 2j+1
                ap[kt][2 * j]     = f2bs(lo.x); an[kt][2 * j]     = f2bs(lo.y);
                ap[kt][2 * j + 1] = f2bs(hi.x); an[kt][2 * j + 1] = f2bs(hi.y);
            }
        }
        f32x4 accp[4], accn[4];
#pragma unroll
        for (int nt = 0; nt < 4; nt++) { accp[nt] = (f32x4)0.f; accn[nt] = (f32x4)0.f; }
#pragma unroll
        for (int nt = 0; nt < 4; nt++) {
            accp[nt] = __builtin_amdgcn_mfma_f32_16x16x32_bf16(ap[0], bfr[0][nt], accp[nt], 0, 0, 0);
            accp[nt] = __builtin_amdgcn_mfma_f32_16x16x32_bf16(ap[1], bfr[1][nt], accp[nt], 0, 0, 0);
            accn[nt] = __builtin_amdgcn_mfma_f32_16x16x32_bf16(an[0], bfr[0][nt], accn[nt], 0, 0, 0);
            accn[nt] = __builtin_amdgcn_mfma_f32_16x16x32_bf16(an[1], bfr[1][nt], accn[nt], 0, 0, 0);
        }
        float dvr[4];
#pragma unroll
        for (int reg = 0; reg < 4; reg++) {
            int node = t * 16 + lg * 4 + reg;
            dvr[reg] = node < n ? rsqrtf((float)cnt[node] + 1.0f) : 0.f;
        }
#pragma unroll
        for (int nt = 0; nt < 4; nt++)
#pragma unroll
            for (int reg = 0; reg < 4; reg++) {
                int node = t * 16 + lg * 4 + reg;
                if (node < n)
                    out[(size_t)node * 64 + nt * 16 + l15] =
                        packfp8(accp[nt][reg] * dvr[reg], accn[nt][reg] * dvr[reg]);
            }
    }
}

// ---- fused GCN aggregation: scalar-pipe addressing + packed f32x2 adds ----
template <int MODE>
__global__ __launch_bounds__(256) void conv_packed(
        const ushort* __restrict__ g, const int* __restrict__ bucket,
        const int* __restrict__ off, const int* __restrict__ cnt,
        const float* __restrict__ bias,
        ushort* __restrict__ out, float* __restrict__ colpart, int n) {
    int lane = threadIdx.x & 63, wid = threadIdx.x >> 6;
    const uchar* gb = (const uchar*)g;
    uint l2 = (uint)lane * 2;
    __shared__ float s[256];
    float colp  = 0.f;
    float blane = bias[lane];
    int wstart = blockIdx.x * 4 + wid, wstride = gridDim.x * 4;
    for (int v = wstart; v < n; v += wstride) {
        int vu  = __builtin_amdgcn_readfirstlane(v);
        int c   = cnt[vu];              // s_load
        int ofs = off[vu];              // s_load
        float dv = rsqrtf((float)c + 1.0f);
        f32x2 acc0 = unpackfp8(*(const ushort*)(gb + ((size_t)(uint)vu << 7) + l2));
        f32x2 acc1 = {0.f, 0.f}, acc2 = {0.f, 0.f}, acc3 = {0.f, 0.f};
        f32x2 acc4 = {0.f, 0.f}, acc5 = {0.f, 0.f}, acc6 = {0.f, 0.f}, acc7 = {0.f, 0.f};
        const int*  bk  = bucket + ofs;            // uniform base
        const int4* bk4 = (const int4*)bk;
        int nq16 = c >> 4;
        for (int q = 0; q < nq16; q++) {           // 16 gathers in flight
            int4 ra = bk4[4 * q],     rb = bk4[4 * q + 1];
            int4 rc = bk4[4 * q + 2], rd = bk4[4 * q + 3];
            uint u0  = *(const ushort*)(gb + ((size_t)(uint)ra.x << 7) + l2);
            uint u1  = *(const ushort*)(gb + ((size_t)(uint)ra.y << 7) + l2);
            uint u2  = *(const ushort*)(gb + ((size_t)(uint)ra.z << 7) + l2);
            uint u3  = *(const ushort*)(gb + ((size_t)(uint)ra.w << 7) + l2);
            uint u4  = *(const ushort*)(gb + ((size_t)(uint)rb.x << 7) + l2);
            uint u5  = *(const ushort*)(gb + ((size_t)(uint)rb.y << 7) + l2);
            uint u6  = *(const ushort*)(gb + ((size_t)(uint)rb.z << 7) + l2);
            uint u7  = *(const ushort*)(gb + ((size_t)(uint)rb.w << 7) + l2);
            uint u8  = *(const ushort*)(gb + ((size_t)(uint)rc.x << 7) + l2);
            uint u9  = *(const ushort*)(gb + ((size_t)(uint)rc.y << 7) + l2);
            uint u10 = *(const ushort*)(gb + ((size_t)(uint)rc.z << 7) + l2);
            uint u11 = *(const ushort*)(gb + ((size_t)(uint)rc.w << 7) + l2);
            uint u12 = *(const ushort*)(gb + ((size_t)(uint)rd.x << 7) + l2);
            uint u13 = *(const ushort*)(gb + ((size_t)(uint)rd.y << 7) + l2);
            uint u14 = *(const ushort*)(gb + ((size_t)(uint)rd.z << 7) + l2);
            uint u15 = *(const ushort*)(gb + ((size_t)(uint)rd.w << 7) + l2);
            acc0 += unpackfp8(u0);  acc1 += unpackfp8(u1);
            acc2 += unpackfp8(u2);  acc3 += unpackfp8(u3);
            acc4 += unpackfp8(u4);  acc5 += unpackfp8(u5);
            acc6 += unpackfp8(u6);  acc7 += unpackfp8(u7);
            acc0 += unpackfp8(u8);  acc1 += unpackfp8(u9);
            acc2 += unpackfp8(u10); acc3 += unpackfp8(u11);
            acc4 += unpackfp8(u12); acc5 += unpackfp8(u13);
            acc6 += unpackfp8(u14); acc7 += unpackfp8(u15);
        }
        int i = nq16 << 4;
        for (; i + 4 <= c; i += 4) {
            int4 r = *(const int4*)(bk + i);
            acc0 += unpackfp8(*(const ushort*)(gb + ((size_t)(uint)r.x << 7) + l2));
            acc1 += unpackfp8(*(const ushort*)(gb + ((size_t)(uint)r.y << 7) + l2));
            acc2 += unpackfp8(*(const ushort*)(gb + ((size_t)(uint)r.z << 7) + l2));
            acc3 += unpackfp8(*(const ushort*)(gb + ((size_t)(uint)r.w << 7) + l2));
        }
        for (; i < c; i++) {
            int r = bk[i];
            acc0 += unpackfp8(*(const ushort*)(gb + ((size_t)(uint)r << 7) + l2));
        }
        f32x2 acc = ((acc0 + acc1) + (acc2 + acc3)) + ((acc4 + acc5) + (acc6 + acc7));
        float rp = fmaf(dv, acc.x, blane);
        float rn = fmaf(dv, acc.y, blane);
        size_t vo = (size_t)vu * 64 + lane;
        if (MODE == 0) {
            out[vo] = packfp8(fmaxf(rp, 0.f), fmaxf(rn, 0.f));
        } else {
            out[vo] = packfp8(rp, rn);
            colp += rp;          // f32 partial (pre-rounding) for summary
        }
    }
    if (MODE == 1) {
        s[wid * 64 + lane] = colp;
        __syncthreads();
        if (wid == 0) {
            float t = s[lane] + s[64 + lane] + s[128 + lane] + s[192 + lane];
            colpart[(size_t)blockIdx.x * 64 + lane] = t;
        }
    }
}

// ---- stage A: sum RB colpart rows per block -> colpart2 --------------------
__global__ __launch_bounds__(256) void colreduce_kernel(
        const float* __restrict__ colpart, float* __restrict__ colpart2) {
    int lane = threadIdx.x & 63, w = threadIdx.x >> 6;
    __shared__ float s4[4][64];
    float t = 0.f;
    int base = blockIdx.x * RB;
    for (int g = w; g < RB; g += 4) t += colpart[(size_t)(base + g) * 64 + lane];
    s4[w][lane] = t;
    __syncthreads();
    if (w == 0)
        colpart2[(size_t)blockIdx.x * 64 + lane] =
            s4[0][lane] + s4[1][lane] + s4[2][lane] + s4[3][lane];
}

// ---- summary + ws = W_dgi @ sigmoid(mean(pos_z)) ---------------------------
__global__ void summary_kernel(const float* __restrict__ colpart,
                               const float* __restrict__ Wdgi,
                               float* __restrict__ wsv, int G, float invN) {
    __shared__ float sm[64];
    __shared__ float s4[4][64];
    int lane = threadIdx.x & 63, w = threadIdx.x >> 6;
    float t = 0.f;
    for (int g = w; g < G; g += 4) t += colpart[(size_t)g * 64 + lane];
    s4[w][lane] = t;
    __syncthreads();
    if (w == 0) {
        t = s4[0][lane] + s4[1][lane] + s4[2][lane] + s4[3][lane];
        sm[lane] = 1.f / (1.f + expf(-t * invN));
    }
    __syncthreads();
    if (threadIdx.x < 64) {
        float a = 0.f;
        for (int j = 0; j < 64; j++) a += Wdgi[threadIdx.x * 64 + j] * sm[j];
        wsv[threadIdx.x] = a;
    }
}

// ---- both losses: 16-lane group per node, 4 nodes per wave-iteration -------
__global__ __launch_bounds__(256) void loss4_kernel(
        const ushort* __restrict__ z, const float* __restrict__ wsv,
        float* __restrict__ lossacc, int n) {
    int lane = threadIdx.x & 63, wid = threadIdx.x >> 6;
    int sub = lane >> 4, dch = lane & 15;
    __shared__ float s[16];
    float w0 = wsv[dch * 4], w1 = wsv[dch * 4 + 1];
    float w2 = wsv[dch * 4 + 2], w3 = wsv[dch * 4 + 3];
    float lp = 0.f, ln = 0.f;
    int nq = (n + 3) >> 2;
    for (int qi = blockIdx.x * 4 + wid; qi < nq; qi += gridDim.x * 4) {
        int v = qi * 4 + sub;
        float p = 0.f, q = 0.f;
        if (v < n) {
            uint2 u = *(const uint2*)(z + (size_t)v * 64 + dch * 4);   // 4 dims
            f32x2 a0 = unpackfp8(u.x), a1 = unpackfp8_hi(u.x);
            f32x2 a2 = unpackfp8(u.y), a3 = unpackfp8_hi(u.y);
            p = a0.x * w0 + a1.x * w1 + a2.x * w2 + a3.x * w3;
            q = a0.y * w0 + a1.y * w1 + a2.y * w2 + a3.y * w3;
        }
        for (int o = 1; o < 16; o <<= 1) {
            p += __shfl_xor(p, o, 64);
            q += __shfl_xor(q, o, 64);
        }
        if (dch == 0 && v < n) {
            lp += -logf(1.f / (1.f + expf(-p)) + 1e-15f);   // -log(sigmoid(p)+eps)
            ln += -logf(1.f / (1.f + expf( q)) + 1e-15f);   // -log(1-sigmoid(q)+eps)
        }
    }
    lp += __shfl_xor(lp, 16, 64); ln += __shfl_xor(ln, 16, 64);
    lp += __shfl_xor(lp, 32, 64); ln += __shfl_xor(ln, 32, 64);
    if (lane == 0) { s[wid] = lp; s[8 + wid] = ln; }
    __syncthreads();
    if (threadIdx.x == 0) atomicAdd(&lossacc[0], s[0] + s[1] + s[2] + s[3]);
    if (threadIdx.x == 1) atomicAdd(&lossacc[1], s[8] + s[9] + s[10] + s[11]);
}

__global__ void finalize_kernel(const float* __restrict__ lossacc,
                                float* __restrict__ out, float invN) {
    out[0] = (lossacc[0] + lossacc[1]) * invN;
}

// ---------------------------------------------------------------------------
extern "C" void kernel_launch(void* const* d_in, const int* in_sizes, int n_in,
                              void* d_out, int out_size, void* d_ws, size_t ws_size,
                              hipStream_t stream) {
    const float* x    = (const float*)d_in[0];
    const float* W1   = (const float*)d_in[1];
    const float* b1   = (const float*)d_in[2];
    const float* W2   = (const float*)d_in[3];
    const float* b2   = (const float*)d_in[4];
    const float* Wdgi = (const float*)d_in[5];
    const int*   edge = (const int*)d_in[6];
    const int*   perm = (const int*)d_in[7];

    const int N = in_sizes[7];
    const int E = in_sizes[6] / 2;
    const int* row = edge;
    const int* col = edge + E;
    const int nb = (N + NPB - 1) >> NB_SHIFT;

    char* wsb = (char*)d_ws;
    size_t woff = 0;
    auto alloc = [&](size_t bytes) -> void* {
        void* p = wsb + woff;
        woff = (woff + bytes + 255) & ~(size_t)255;
        return p;
    };
    int*    bucket   = (int*)  alloc((size_t)nb * BINREGION * 4);  // 9.6 MB
    uint*   bins     = (uint*) alloc((size_t)nb * BINCAP * 4);     // 8 MB
    int*    bincnt   = (int*)  alloc((size_t)nb * 4);
    int*    cnt      = (int*)  alloc((size_t)N * 4);
    int*    off      = (int*)  alloc((size_t)N * 4);
    ushort* G        = (ushort*)alloc((size_t)N * 64 * 2);         // fp8-packed, 12.8 MB
    ushort* H        = (ushort*)alloc((size_t)N * 64 * 2);         // fp8-packed, 12.8 MB
    float*  colpart  = (float*)alloc((size_t)GG * 64 * 4);
    float*  colpart2 = (float*)alloc((size_t)(GG / RB) * 64 * 4);
    float*  wsv      = (float*)alloc(64 * 4);
    float*  lossacc  = (float*)alloc(2 * 4);

    zero_kernel<<<1, 256, 0, stream>>>(bincnt, lossacc, nb);

    const int nchunks = (E + PCHUNK - 1) / PCHUNK;
    partition_edges<<<nchunks, 256, 0, stream>>>(row, col, bins, bincnt, E, nb);
    place_lds<<<nb, 256, 0, stream>>>(bins, bincnt, bucket, off, cnt, N);

    // layer 1: G = fp8((X @ W1) * dis) both branches, aggregate+relu -> H (fp8)
    gemm1_mfma<<<1024, 256, 0, stream>>>(x, W1, perm, cnt, G, N);
    conv_packed<0><<<GG, 256, 0, stream>>>(G, bucket, off, cnt, b1, H, nullptr, N);
    // layer 2: G = fp8((H @ W2) * dis), aggregate -> z (fp8, in H) + colpart
    gemm2_mfma<<<1024, 256, 0, stream>>>(H, W2, cnt, G, N);
    conv_packed<1><<<GG, 256, 0, stream>>>(G, bucket, off, cnt, b2, H, colpart, N);

    colreduce_kernel<<<GG / RB, 256, 0, stream>>>(colpart, colpart2);
    summary_kernel<<<1, 256, 0, stream>>>(colpart2, Wdgi, wsv, GG / RB, 1.0f / N);
    loss4_kernel<<<1024, 256, 0, stream>>>(H, wsv, lossacc, N);
    finalize_kernel<<<1, 1, 0, stream>>>(lossacc, (float*)d_out, 1.0f / N);
}